// Round 7
// baseline (623.059 us; speedup 1.0000x reference)
//
#include <hip/hip_runtime.h>

typedef __bf16 bf16;
typedef __bf16 bf16x4 __attribute__((ext_vector_type(4)));
typedef __bf16 bf16x8 __attribute__((ext_vector_type(8)));
typedef float f32x4 __attribute__((ext_vector_type(4)));
typedef float f32x2 __attribute__((ext_vector_type(2)));
typedef _Float16 f16x2 __attribute__((ext_vector_type(2)));

#define S 2048
#define DM 2048
#define HD 128
#define H 16
#define NQKV 3072
#define NEWTON_ITERS 12
#define BROW 556         // f32 row stride of LDS buf; keeps LDS bank conflicts at 0 (R3-R6)
#define MASKV -30000.0f  // causal-mask value; f16-representable, dominates all real scores

__device__ __forceinline__ void gl2lds16(const void* g, void* l) {
    __builtin_amdgcn_global_load_lds(
        (const __attribute__((address_space(1))) void*)g,
        (__attribute__((address_space(3))) void*)l, 16, 0, 0);
}

__device__ __forceinline__ void nt_store4(f32x4 v, float* p) {
    __builtin_nontemporal_store(v, (f32x4*)p);
}

// ---------------- DPP-based wave(64) reductions: VALU-latency chains, no LDS pipe ----------------
template <int CTRL, int RM>
__device__ __forceinline__ float dpp_zero(float x) {  // invalid/disabled lanes contribute 0
    return __builtin_bit_cast(float, __builtin_amdgcn_update_dpp(
        0, __builtin_bit_cast(int, x), CTRL, RM, 0xf, false));
}
template <int CTRL, int RM>
__device__ __forceinline__ float dpp_self(float x) {  // invalid/disabled lanes contribute x (no-op for max)
    int xi = __builtin_bit_cast(int, x);
    return __builtin_bit_cast(float, __builtin_amdgcn_update_dpp(xi, xi, CTRL, RM, 0xf, false));
}
__device__ __forceinline__ float wave_bcast63(float x) {
    return __builtin_bit_cast(float, __builtin_amdgcn_readlane(__builtin_bit_cast(int, x), 63));
}
__device__ __forceinline__ float wave_sum(float x) {
    x += dpp_zero<0x111, 0xf>(x);  // row_shr:1
    x += dpp_zero<0x112, 0xf>(x);  // row_shr:2
    x += dpp_zero<0x114, 0xf>(x);  // row_shr:4
    x += dpp_zero<0x118, 0xf>(x);  // row_shr:8  -> lane15 of each row-of-16 = row sum
    x += dpp_zero<0x142, 0xa>(x);  // row_bcast:15 -> rows 1,3
    x += dpp_zero<0x143, 0xc>(x);  // row_bcast:31 -> rows 2,3; lane63 = total
    return wave_bcast63(x);
}
__device__ __forceinline__ float wave_fmax(float x) {
    x = fmaxf(x, dpp_self<0x111, 0xf>(x));
    x = fmaxf(x, dpp_self<0x112, 0xf>(x));
    x = fmaxf(x, dpp_self<0x114, 0xf>(x));
    x = fmaxf(x, dpp_self<0x118, 0xf>(x));
    x = fmaxf(x, dpp_self<0x142, 0xa>(x));
    x = fmaxf(x, dpp_self<0x143, 0xc>(x));
    return wave_bcast63(x);
}

// ---------------- fused fp32 -> bf16 convert for all 5 inputs (float4 granules) ----------------
__global__ void cvt_all(const float* __restrict__ hid, const float* __restrict__ wq,
                        const float* __restrict__ wk, const float* __restrict__ wv,
                        const float* __restrict__ wo, bf16* __restrict__ bh,
                        bf16* __restrict__ bqkv, bf16* __restrict__ bwo) {
    int i = blockIdx.x * blockDim.x + threadIdx.x;
    const float* src;
    bf16* dst;
    int off;
    if (i < 1048576) { src = hid; dst = bh; off = i; }
    else if (i < 2097152) { src = wq; dst = bqkv; off = i - 1048576; }
    else if (i < 2359296) { src = wk; dst = bqkv + 2048 * 2048; off = i - 2097152; }
    else if (i < 2621440) { src = wv; dst = bqkv + 2048 * 2048 + 512 * 2048; off = i - 2359296; }
    else { src = wo; dst = bwo; off = i - 2621440; }
    float4 f = ((const float4*)src)[off];
    bf16x4 o;
    o[0] = (bf16)f.x; o[1] = (bf16)f.y; o[2] = (bf16)f.z; o[3] = (bf16)f.w;
    ((bf16x4*)dst)[off] = o;
}

// ---------------- BMxBN-tile GEMM: C[m][n] = sum_k A[m][k]*B[n][k] ----------------
// 2-phase pipeline: LDS double buffer; next tile's global_load_lds issued BEFORE
// current tile's ds_read+MFMA; single barrier per K-step.
template <int BM, int BN>
__global__ __launch_bounds__(256) void gemm_bt(const bf16* __restrict__ A,
                                               const bf16* __restrict__ B,
                                               float* __restrict__ C, int Ndim, int K) {
    __shared__ bf16 As[2][BM * 32];
    __shared__ bf16 Bs[2][BN * 32];
    int m0 = blockIdx.x * BM, n0 = blockIdx.y * BN;
    int t = threadIdx.x;
    int l = t & 63, w = t >> 6;
    int lane16 = l & 15, quad = l >> 4;

    const bf16* Abase = A + (size_t)m0 * K;
    const bf16* Bbase = B + (size_t)n0 * K;

    constexpr int MI = BM / 32, NI = BN / 32;
    int wm = (w & 1) * (BM / 2), wn = (w >> 1) * (BN / 2);
    f32x4 acc[MI][NI];
#pragma unroll
    for (int i = 0; i < MI; i++)
#pragma unroll
        for (int j = 0; j < NI; j++) acc[i][j] = (f32x4){0.f, 0.f, 0.f, 0.f};

    constexpr int AG = BM * 4;  // 16B granules in A tile
    constexpr int BG = BN * 4;

    auto stage = [&](int sel, int k0) {
#pragma unroll
        for (int it = 0; it < AG / 256; it++) {
            int c = it * 256 + t;  // granule index; c - l is wave-uniform
            gl2lds16(Abase + (size_t)(c >> 2) * K + k0 + (c & 3) * 8, &As[sel][(c - l) * 8]);
        }
#pragma unroll
        for (int it = 0; it < BG / 256; it++) {
            int c = it * 256 + t;
            gl2lds16(Bbase + (size_t)(c >> 2) * K + k0 + (c & 3) * 8, &Bs[sel][(c - l) * 8]);
        }
    };

    stage(0, 0);
    __syncthreads();
    int cur = 0;
    for (int k0 = 0; k0 < K; k0 += 32) {
        if (k0 + 32 < K) stage(cur ^ 1, k0 + 32);  // prefetch overlaps ds_read+MFMA below
        bf16x8 af[MI], bfr[NI];
#pragma unroll
        for (int i = 0; i < MI; i++)
            af[i] = *(const bf16x8*)&As[cur][(wm + i * 16 + lane16) * 32 + quad * 8];
#pragma unroll
        for (int j = 0; j < NI; j++)
            bfr[j] = *(const bf16x8*)&Bs[cur][(wn + j * 16 + lane16) * 32 + quad * 8];
#pragma unroll
        for (int i = 0; i < MI; i++)
#pragma unroll
            for (int j = 0; j < NI; j++)
                acc[i][j] = __builtin_amdgcn_mfma_f32_16x16x32_bf16(af[i], bfr[j], acc[i][j], 0, 0, 0);
        __syncthreads();  // one barrier/K-step: drains prefetch (vmcnt) + orders LDS reuse
        cur ^= 1;
    }
#pragma unroll
    for (int i = 0; i < MI; i++)
#pragma unroll
        for (int j = 0; j < NI; j++) {
            float* cp = C + (size_t)(m0 + wm + i * 16 + quad * 4) * Ndim + n0 + wn + j * 16 + lane16;
#pragma unroll
            for (int r = 0; r < 4; r++) cp[(size_t)r * Ndim] = acc[i][j][r];
        }
}

// ---------------- RoPE for q/k (cols 0..2559), coalesced in col ----------------
__global__ void rope_qk(const float* __restrict__ qkv, const float* __restrict__ cosb,
                        const float* __restrict__ sinb, bf16* __restrict__ qs,
                        bf16* __restrict__ kb) {
    int col = blockIdx.x * 256 + threadIdx.x;  // 0..2559
    int s = blockIdx.y;
    const float* row = qkv + (size_t)s * NQKV;
    float v = row[col];
    if (col < DM) {
        int h = col >> 7, d = col & 127;
        float c = cosb[s * HD + d], sn = sinb[s * HD + d];
        float other = row[(h << 7) + ((d < 64) ? (d + 64) : (d - 64))];
        float rot = (d < 64) ? -other : other;
        float o = v * c + rot * sn;
        qs[((size_t)h * S + s) * HD + d] = (bf16)(o * 0.04419417382415922f);  // HD^-0.5 * (alpha-1)
    } else {
        int c2 = col - DM;
        int kv = c2 >> 7, d = c2 & 127;
        float c = cosb[s * HD + d], sn = sinb[s * HD + d];
        float other = row[DM + (kv << 7) + ((d < 64) ? (d + 64) : (d - 64))];
        float rot = (d < 64) ? -other : other;
        float o = v * c + rot * sn;
        kb[((size_t)kv * S + s) * HD + d] = (bf16)o;
    }
}

// ---------------- V transpose via LDS tile: qkv[s][2560+y] -> vT[y][s] bf16 ----------------
__global__ __launch_bounds__(256) void vtrans(const float* __restrict__ qkv, bf16* __restrict__ vT) {
    __shared__ bf16 tile[64][66];
    int s0 = blockIdx.x * 64, y0 = blockIdx.y * 64;
    int t = threadIdx.x;
    int ty = t & 63, tr = t >> 6;
#pragma unroll
    for (int i = 0; i < 16; i++) {
        int s = tr + i * 4;
        float v = qkv[(size_t)(s0 + s) * NQKV + 2560 + y0 + ty];  // coalesced read
        tile[s][ty] = (bf16)v;
    }
    __syncthreads();
#pragma unroll
    for (int i = 0; i < 16; i++) {
        int y = tr + i * 4;
        vT[(size_t)(y0 + y) * S + s0 + ty] = tile[ty][y];  // coalesced write
    }
}

// ------- fused: scores (MFMA) + causal mask + entmax Newton + P.V (MFMA) + attn write -------
// 16-wave (1024-thread) blocks, ONE row per wave (small per-wave live set), f16-packed
// score row (16 VGPR). NO occupancy attribute: R2-R5 showed any waves_per_eu/launch_bounds
// min-wave constraint makes the allocator starve the arch half of the unified file and
// spill xr (~90 MB scratch). Natural allocation here ~<=64 total -> 2 blocks/CU (R2
// demonstrated 80% occ at 34 KB LDS) with zero spill (R6 demonstrated no-attr = no spill).
template <int SEGS>
__device__ __forceinline__ void attn_body(const bf16* __restrict__ qs, const bf16* __restrict__ kb,
                                          const bf16* __restrict__ vT, float* __restrict__ attn,
                                          bf16* __restrict__ o, int r0, int h,
                                          float (&buf)[16][BROW]) {
    constexpr int NR = SEGS * 4;  // f16x2 regs per lane (= SEGS*8 scores)
    int jlen = r0 + 16;
    int l = threadIdx.x & 63;
    int w = threadIdx.x >> 6;  // 0..15
    int lane16 = l & 15, quad = l >> 4;

    const bf16* qrow = qs + ((size_t)h * S + (r0 + lane16)) * HD + quad * 8;
    bf16x8 afrag[4];
#pragma unroll
    for (int kc = 0; kc < 4; kc++) afrag[kc] = *(const bf16x8*)(qrow + kc * 32);

    const bf16* kbase = kb + (size_t)(h >> 2) * S * HD;
    const bf16* vbase = vT + (size_t)(h >> 2) * HD * S;
    f16x2 xr[NR];

    // ---- Phase A: scores into packed-f16 registers; single f32 buffer, 2 barriers/segment ----
#pragma unroll
    for (int sgi = 0; sgi < SEGS; sgi++) {
        int j0 = sgi * 512;
#pragma unroll
        for (int tt = 0; tt < 2; tt++) {
            int t = w + tt * 16;
            int jt = j0 + t * 16;
            if (jt < jlen) {
                f32x4 acc = {0.f, 0.f, 0.f, 0.f};
                const bf16* kp = kbase + (size_t)(jt + lane16) * HD + quad * 8;
#pragma unroll
                for (int kc = 0; kc < 4; kc++) {
                    bf16x8 b = *(const bf16x8*)(kp + kc * 32);
                    acc = __builtin_amdgcn_mfma_f32_16x16x32_bf16(afrag[kc], b, acc, 0, 0, 0);
                }
                if (jt + 15 > r0) {  // diagonal tile: apply causal mask
                    int jj = jt + lane16;
#pragma unroll
                    for (int r = 0; r < 4; r++) {
                        int rowi = quad * 4 + r;
                        float v = acc[r];
                        if (jj > r0 + rowi) v = MASKV;
                        buf[rowi][t * 16 + lane16] = v;
                    }
                } else {
#pragma unroll
                    for (int r = 0; r < 4; r++) buf[quad * 4 + r][t * 16 + lane16] = acc[r];
                }
            }
        }
        __syncthreads();
#pragma unroll
        for (int part = 0; part < 2; part++) {
            float4 fq = *(const float4*)&buf[w][part * 256 + l * 4];
            f32x2 lo, hi;
            if (sgi == SEGS - 1) {
                int jb = j0 + part * 256 + l * 4;
                lo = (f32x2){(jb + 0 < jlen) ? fq.x : MASKV, (jb + 1 < jlen) ? fq.y : MASKV};
                hi = (f32x2){(jb + 2 < jlen) ? fq.z : MASKV, (jb + 3 < jlen) ? fq.w : MASKV};
            } else {
                lo = (f32x2){fq.x, fq.y};
                hi = (f32x2){fq.z, fq.w};
            }
            xr[sgi * 4 + part * 2 + 0] = __builtin_convertvector(lo, f16x2);
            xr[sgi * 4 + part * 2 + 1] = __builtin_convertvector(hi, f16x2);
        }
        __syncthreads();  // protect buffer before next segment's writes
    }

    // ---- Phase B: entmax-1.5 tau via Newton-from-below (wave w owns row r0+w) ----
    const f32x2 z2 = {0.f, 0.f};
    float mx = MASKV;
#pragma unroll
    for (int c = 0; c < NR; c++) {
        f32x2 x0 = __builtin_convertvector(xr[c], f32x2);
        mx = fmaxf(mx, fmaxf(x0[0], x0[1]));
    }
    float m = wave_fmax(mx);

    float tau = m - 1.0f;
#pragma unroll 1
    for (int it = 0; it < NEWTON_ITERS; it++) {
        f32x2 tvi = {tau, tau};
        f32x2 fa = z2, fb = z2, ga = z2, gb = z2;
#pragma unroll
        for (int c = 0; c < NR; c += 2) {
            f32x2 x0 = __builtin_convertvector(xr[c], f32x2);
            f32x2 t0 = __builtin_elementwise_max(x0 - tvi, z2);
            fa += t0 * t0; ga += t0;
            f32x2 x1 = __builtin_convertvector(xr[c + 1], f32x2);
            f32x2 t1 = __builtin_elementwise_max(x1 - tvi, z2);
            fb += t1 * t1; gb += t1;
        }
        f32x2 fv = fa + fb, gv = ga + gb;
        float f = wave_sum(fv[0] + fv[1]);
        float g = wave_sum(gv[0] + gv[1]);
        tau += (f - 1.0f) / (2.0f * g + 1e-20f);
    }

    f32x2 tv = {tau, tau};
    float inv;
    {
        f32x2 sa = z2, sbv = z2;
#pragma unroll
        for (int c = 0; c < NR; c += 2) {
            f32x2 x0 = __builtin_convertvector(xr[c], f32x2);
            f32x2 t0 = __builtin_elementwise_max(x0 - tv, z2);
            sa += t0 * t0;
            f32x2 x1 = __builtin_convertvector(xr[c + 1], f32x2);
            f32x2 t1 = __builtin_elementwise_max(x1 - tv, z2);
            sbv += t1 * t1;
        }
        f32x2 sv = sa + sbv;
        float ssum = wave_sum(sv[0] + sv[1]);
        inv = 1.0f / ssum;
    }

    // ---- Phase C: P bf16 -> LDS (ping-pong halves), P.V MFMA; 1 barrier/segment ----
    int jt_o = (w & 7) * 16;
    int kh = (w >> 3) * 256;
    f32x4 acc_o = {0.f, 0.f, 0.f, 0.f};
    f32x2 inv2 = {inv, inv};

#pragma unroll
    for (int sgi = 0; sgi < SEGS; sgi++) {
        int j0 = sgi * 512;
        bf16 (*pb)[BROW] = (bf16(*)[BROW])(&buf[0][0]) + (sgi & 1) * 16;
#pragma unroll
        for (int part = 0; part < 2; part++) {
            f32x2 xa = __builtin_convertvector(xr[sgi * 4 + part * 2 + 0], f32x2);
            f32x2 xb = __builtin_convertvector(xr[sgi * 4 + part * 2 + 1], f32x2);
            f32x2 ta = __builtin_elementwise_max(xa - tv, z2);
            f32x2 tb = __builtin_elementwise_max(xb - tv, z2);
            f32x2 pa = (ta * ta) * inv2;
            f32x2 pb2 = (tb * tb) * inv2;
            bf16x4 pbv;
            pbv[0] = (bf16)pa[0]; pbv[1] = (bf16)pa[1];
            pbv[2] = (bf16)pb2[0]; pbv[3] = (bf16)pb2[1];
            *(bf16x4*)&pb[w][part * 256 + l * 4] = pbv;
        }
        __syncthreads();
#pragma unroll
        for (int ks = 0; ks < 8; ks++) {
            int kk = kh + ks * 32;
            bf16x8 a = *(const bf16x8*)&pb[lane16][kk + quad * 8];
            bf16x8 b = *(const bf16x8*)(vbase + (size_t)(jt_o + lane16) * S + j0 + kk + quad * 8);
            acc_o = __builtin_amdgcn_mfma_f32_16x16x32_bf16(a, b, acc_o, 0, 0, 0);
        }
        // no trailing barrier: next segment writes the other half; its barrier orders reuse
    }

    // ---- Phase D: combine K-halves, write O ----
    __syncthreads();  // all P.V MFMA reads done before buf reuse as f32
    if (w >= 8) {
#pragma unroll
        for (int r = 0; r < 4; r++) buf[w - 8][l * 4 + r] = acc_o[r];
    }
    __syncthreads();
    if (w < 8) {
        bf16* op = o + (size_t)(r0 + quad * 4) * DM + h * HD + jt_o + lane16;
#pragma unroll
        for (int r = 0; r < 4; r++) {
            float v = acc_o[r] + buf[w][l * 4 + r];
            op[(size_t)r * DM] = (bf16)v;
        }
    }

    // ---- Phase E: full attn row streaming write (P + zeros); no barrier after -> drains lazily ----
    float* arow = attn + ((size_t)h * S + (r0 + w)) * S;
#pragma unroll
    for (int sgi = 0; sgi < SEGS; sgi++) {
        int j0 = sgi * 512;
#pragma unroll
        for (int part = 0; part < 2; part++) {
            f32x2 xa = __builtin_convertvector(xr[sgi * 4 + part * 2 + 0], f32x2);
            f32x2 xb = __builtin_convertvector(xr[sgi * 4 + part * 2 + 1], f32x2);
            f32x2 ta = __builtin_elementwise_max(xa - tv, z2);
            f32x2 tb = __builtin_elementwise_max(xb - tv, z2);
            f32x2 pa = (ta * ta) * inv2;
            f32x2 pb2 = (tb * tb) * inv2;
            f32x4 pv = {pa[0], pa[1], pb2[0], pb2[1]};
            nt_store4(pv, &arow[j0 + part * 256 + l * 4]);
        }
    }
    f32x4 z4 = {0.f, 0.f, 0.f, 0.f};
    for (int j = SEGS * 512 + l * 4; j < S; j += 256) nt_store4(z4, &arow[j]);
}

// 512 blocks x 1024 threads: each block runs classes {4,3,2,1} = 10 segments (uniform),
// targeting 2 resident blocks/CU via natural (unconstrained) register allocation.
__global__ __attribute__((amdgpu_flat_work_group_size(1024, 1024)))
void attn_av_all(const bf16* __restrict__ qs,
                 const bf16* __restrict__ kb,
                 const bf16* __restrict__ vT,
                 float* __restrict__ attn,
                 bf16* __restrict__ o) {
    __shared__ float buf[16][BROW];  // ~35 KB -> 2 blocks/CU fit LDS
    int b = blockIdx.x;  // 0..511
    int h = b & 15;
    int qh = b >> 4;     // 0..31
    attn_body<4>(qs, kb, vT, attn, o, (96 + qh) * 16, h, buf);
    __syncthreads();
    attn_body<3>(qs, kb, vT, attn, o, (64 + qh) * 16, h, buf);
    __syncthreads();
    attn_body<2>(qs, kb, vT, attn, o, (32 + qh) * 16, h, buf);
    __syncthreads();
    attn_body<1>(qs, kb, vT, attn, o, qh * 16, h, buf);
}

extern "C" void kernel_launch(void* const* d_in, const int* in_sizes, int n_in,
                              void* d_out, int out_size, void* d_ws, size_t ws_size,
                              hipStream_t stream) {
    const float* hidden = (const float*)d_in[0];
    const float* cosb   = (const float*)d_in[1];
    const float* sinb   = (const float*)d_in[2];
    const float* wq     = (const float*)d_in[3];
    const float* wk     = (const float*)d_in[4];
    const float* wv     = (const float*)d_in[5];
    const float* wo     = (const float*)d_in[6];
    char* ws = (char*)d_ws;
    bf16*  bf_hidden = (bf16*)(ws);                    // 8 MB; reused as O bf16 later
    bf16*  bf_wqkv   = (bf16*)(ws + 8388608);          // 12 MB
    bf16*  bf_wo     = (bf16*)(ws + 20971520);         // 8 MB
    float* qkv_raw   = (float*)(ws + 29360128);        // 24 MB
    bf16*  qsb       = (bf16*)(ws + 54525952);         // 8 MB  [H][S][HD]
    bf16*  kbb       = (bf16*)(ws + 62914560);         // 2 MB  [4][S][HD]
    bf16*  vTb       = (bf16*)(ws + 65011712);         // 2 MB  [4][HD][S]
    float* out  = (float*)d_out;
    float* attn = out + 4194304;

    cvt_all<<<dim3(14336), 256, 0, stream>>>(hidden, wq, wk, wv, wo, bf_hidden, bf_wqkv, bf_wo);

    // QKV projection: [2048 x 2048] @ [3072 x 2048]^T
    gemm_bt<64, 128><<<dim3(32, 24), 256, 0, stream>>>(bf_hidden, bf_wqkv, qkv_raw, NQKV, DM);

    rope_qk<<<dim3(10, S), 256, 0, stream>>>(qkv_raw, cosb, sinb, qsb, kbb);
    vtrans<<<dim3(32, 8), 256, 0, stream>>>(qkv_raw, vTb);

    // fused scores + entmax + P.V + attn write  (512 blocks x 1024 threads, 2/CU target)
    attn_av_all<<<dim3(512), 1024, 0, stream>>>(qsb, kbb, vTb, attn, bf_hidden);

    // out = O @ wo^T
    gemm_bt<64, 128><<<dim3(32, 16), 256, 0, stream>>>(bf_hidden, bf_wo, out, DM, DM);
}

// Round 8
// 586.826 us; speedup vs baseline: 1.0617x; 1.0617x over previous
//
#include <hip/hip_runtime.h>

typedef __bf16 bf16;
typedef __bf16 bf16x4 __attribute__((ext_vector_type(4)));
typedef __bf16 bf16x8 __attribute__((ext_vector_type(8)));
typedef float f32x4 __attribute__((ext_vector_type(4)));
typedef float f32x2 __attribute__((ext_vector_type(2)));

#define S 2048
#define DM 2048
#define HD 128
#define H 16
#define NQKV 3072
#define AS_ITERS 3
#define NW_ITERS 4
#define BROW 556  // f32 row stride of LDS buf; 556%32=12 -> no LDS bank conflicts (R3-R7)

__device__ __forceinline__ void gl2lds16(const void* g, void* l) {
    __builtin_amdgcn_global_load_lds(
        (const __attribute__((address_space(1))) void*)g,
        (__attribute__((address_space(3))) void*)l, 16, 0, 0);
}

__device__ __forceinline__ void nt_store4(f32x4 v, float* p) {
    __builtin_nontemporal_store(v, (f32x4*)p);
}

// ---------------- DPP-based wave(64) reductions ----------------
template <int CTRL, int RM>
__device__ __forceinline__ float dpp_zero(float x) {
    return __builtin_bit_cast(float, __builtin_amdgcn_update_dpp(
        0, __builtin_bit_cast(int, x), CTRL, RM, 0xf, false));
}
template <int CTRL, int RM>
__device__ __forceinline__ float dpp_self(float x) {
    int xi = __builtin_bit_cast(int, x);
    return __builtin_bit_cast(float, __builtin_amdgcn_update_dpp(xi, xi, CTRL, RM, 0xf, false));
}
__device__ __forceinline__ float wave_bcast63(float x) {
    return __builtin_bit_cast(float, __builtin_amdgcn_readlane(__builtin_bit_cast(int, x), 63));
}
__device__ __forceinline__ float wave_sum(float x) {
    x += dpp_zero<0x111, 0xf>(x);
    x += dpp_zero<0x112, 0xf>(x);
    x += dpp_zero<0x114, 0xf>(x);
    x += dpp_zero<0x118, 0xf>(x);
    x += dpp_zero<0x142, 0xa>(x);
    x += dpp_zero<0x143, 0xc>(x);
    return wave_bcast63(x);
}
__device__ __forceinline__ float wave_fmax(float x) {
    x = fmaxf(x, dpp_self<0x111, 0xf>(x));
    x = fmaxf(x, dpp_self<0x112, 0xf>(x));
    x = fmaxf(x, dpp_self<0x114, 0xf>(x));
    x = fmaxf(x, dpp_self<0x118, 0xf>(x));
    x = fmaxf(x, dpp_self<0x142, 0xa>(x));
    x = fmaxf(x, dpp_self<0x143, 0xc>(x));
    return wave_bcast63(x);
}

// ---------------- fused fp32 -> bf16 convert for all 5 inputs (float4 granules) ----------------
__global__ void cvt_all(const float* __restrict__ hid, const float* __restrict__ wq,
                        const float* __restrict__ wk, const float* __restrict__ wv,
                        const float* __restrict__ wo, bf16* __restrict__ bh,
                        bf16* __restrict__ bqkv, bf16* __restrict__ bwo) {
    int i = blockIdx.x * blockDim.x + threadIdx.x;
    const float* src;
    bf16* dst;
    int off;
    if (i < 1048576) { src = hid; dst = bh; off = i; }
    else if (i < 2097152) { src = wq; dst = bqkv; off = i - 1048576; }
    else if (i < 2359296) { src = wk; dst = bqkv + 2048 * 2048; off = i - 2097152; }
    else if (i < 2621440) { src = wv; dst = bqkv + 2048 * 2048 + 512 * 2048; off = i - 2359296; }
    else { src = wo; dst = bwo; off = i - 2621440; }
    float4 f = ((const float4*)src)[off];
    bf16x4 o;
    o[0] = (bf16)f.x; o[1] = (bf16)f.y; o[2] = (bf16)f.z; o[3] = (bf16)f.w;
    ((bf16x4*)dst)[off] = o;
}

// ---------------- 128x128-tile GEMM (R0-proven) + 2-phase dbuf prefetch ----------------
__global__ __launch_bounds__(256) void gemm128_bt(const bf16* __restrict__ A,
                                                  const bf16* __restrict__ B,
                                                  float* __restrict__ C, int Ndim, int K) {
    __shared__ bf16 As[2][128 * 32];
    __shared__ bf16 Bs[2][128 * 32];
    int m0 = blockIdx.x * 128, n0 = blockIdx.y * 128;
    int t = threadIdx.x;
    int l = t & 63, w = t >> 6;
    int lane16 = l & 15, quad = l >> 4;

    int c0 = (w * 2) * 64 + l;
    int c1 = c0 + 64;
    const bf16* Abase = A + (size_t)m0 * K;
    const bf16* Bbase = B + (size_t)n0 * K;

    int wm = (w & 1) * 64, wn = (w >> 1) * 64;
    f32x4 acc[4][4];
#pragma unroll
    for (int i = 0; i < 4; i++)
#pragma unroll
        for (int j = 0; j < 4; j++) acc[i][j] = (f32x4){0.f, 0.f, 0.f, 0.f};

    auto stage = [&](int sel, int k0) {
        gl2lds16(Abase + (size_t)(c0 >> 2) * K + k0 + (c0 & 3) * 8, &As[sel][(w * 2) * 512]);
        gl2lds16(Abase + (size_t)(c1 >> 2) * K + k0 + (c1 & 3) * 8, &As[sel][(w * 2 + 1) * 512]);
        gl2lds16(Bbase + (size_t)(c0 >> 2) * K + k0 + (c0 & 3) * 8, &Bs[sel][(w * 2) * 512]);
        gl2lds16(Bbase + (size_t)(c1 >> 2) * K + k0 + (c1 & 3) * 8, &Bs[sel][(w * 2 + 1) * 512]);
    };

    stage(0, 0);
    __syncthreads();
    int cur = 0;
    for (int k0 = 0; k0 < K; k0 += 32) {
        if (k0 + 32 < K) stage(cur ^ 1, k0 + 32);  // prefetch overlaps ds_read+MFMA
        bf16x8 af[4], bfr[4];
#pragma unroll
        for (int i = 0; i < 4; i++)
            af[i] = *(const bf16x8*)&As[cur][(wm + i * 16 + lane16) * 32 + quad * 8];
#pragma unroll
        for (int j = 0; j < 4; j++)
            bfr[j] = *(const bf16x8*)&Bs[cur][(wn + j * 16 + lane16) * 32 + quad * 8];
#pragma unroll
        for (int i = 0; i < 4; i++)
#pragma unroll
            for (int j = 0; j < 4; j++)
                acc[i][j] = __builtin_amdgcn_mfma_f32_16x16x32_bf16(af[i], bfr[j], acc[i][j], 0, 0, 0);
        __syncthreads();  // drains prefetch + orders LDS reuse
        cur ^= 1;
    }
#pragma unroll
    for (int i = 0; i < 4; i++)
#pragma unroll
        for (int j = 0; j < 4; j++) {
            float* cp = C + (size_t)(m0 + wm + i * 16 + quad * 4) * Ndim + n0 + wn + j * 16 + lane16;
#pragma unroll
            for (int r = 0; r < 4; r++) cp[(size_t)r * Ndim] = acc[i][j][r];
        }
}

// ---------------- RoPE for q/k (cols 0..2559), coalesced in col ----------------
__global__ void rope_qk(const float* __restrict__ qkv, const float* __restrict__ cosb,
                        const float* __restrict__ sinb, bf16* __restrict__ qs,
                        bf16* __restrict__ kb) {
    int col = blockIdx.x * 256 + threadIdx.x;  // 0..2559
    int s = blockIdx.y;
    const float* row = qkv + (size_t)s * NQKV;
    float v = row[col];
    if (col < DM) {
        int h = col >> 7, d = col & 127;
        float c = cosb[s * HD + d], sn = sinb[s * HD + d];
        float other = row[(h << 7) + ((d < 64) ? (d + 64) : (d - 64))];
        float rot = (d < 64) ? -other : other;
        float o = v * c + rot * sn;
        qs[((size_t)h * S + s) * HD + d] = (bf16)(o * 0.04419417382415922f);  // HD^-0.5 * (alpha-1)
    } else {
        int c2 = col - DM;
        int kv = c2 >> 7, d = c2 & 127;
        float c = cosb[s * HD + d], sn = sinb[s * HD + d];
        float other = row[DM + (kv << 7) + ((d < 64) ? (d + 64) : (d - 64))];
        float rot = (d < 64) ? -other : other;
        float o = v * c + rot * sn;
        kb[((size_t)kv * S + s) * HD + d] = (bf16)o;
    }
}

// ---------------- V transpose via LDS tile: qkv[s][2560+y] -> vT[y][s] bf16 ----------------
__global__ __launch_bounds__(256) void vtrans(const float* __restrict__ qkv, bf16* __restrict__ vT) {
    __shared__ bf16 tile[64][66];
    int s0 = blockIdx.x * 64, y0 = blockIdx.y * 64;
    int t = threadIdx.x;
    int ty = t & 63, tr = t >> 6;
#pragma unroll
    for (int i = 0; i < 16; i++) {
        int s = tr + i * 4;
        float v = qkv[(size_t)(s0 + s) * NQKV + 2560 + y0 + ty];  // coalesced read
        tile[s][ty] = (bf16)v;
    }
    __syncthreads();
#pragma unroll
    for (int i = 0; i < 16; i++) {
        int y = tr + i * 4;
        vT[(size_t)(y0 + y) * S + s0 + ty] = tile[ty][y];  // coalesced write
    }
}

// ------- fused: scores (MFMA) + causal mask + entmax tau + P.V (MFMA) + attn write -------
// R2-proven shape: 16-wave blocks, launch_bounds(1024,8) (VGPR clamp 32; xr spills to
// scratch that lives in L3 — measured FASTER than any no-spill config because 2 blocks/CU
// (80% occ) co-reside). tau solver: 3 active-set (exact quadratic on current support)
// + 4 Newton polish = 9 full-row passes vs Newton-12's 15 -> fewer spill re-reads.
// attn global store fused into Phase C so xr's live range ends there (R3's late store
// grew spill 48->90 MB).
template <int SEGS>
__device__ __forceinline__ void attn_body(const bf16* __restrict__ qs, const bf16* __restrict__ kb,
                                          const bf16* __restrict__ vT, float* __restrict__ attn,
                                          bf16* __restrict__ o, int r0, int h,
                                          float (&buf)[16][BROW]) {
    constexpr int NREG2 = SEGS * 4;  // f32x2 regs per lane (= SEGS*8 scores)
    int jlen = r0 + 16;
    int l = threadIdx.x & 63;
    int w = threadIdx.x >> 6;  // 0..15
    int lane16 = l & 15, quad = l >> 4;

    const bf16* qrow = qs + ((size_t)h * S + (r0 + lane16)) * HD + quad * 8;
    bf16x8 afrag[4];
#pragma unroll
    for (int kc = 0; kc < 4; kc++) afrag[kc] = *(const bf16x8*)(qrow + kc * 32);

    const bf16* kbase = kb + (size_t)(h >> 2) * S * HD;
    const bf16* vbase = vT + (size_t)(h >> 2) * HD * S;
    f32x2 xr[NREG2];

    // ---- Phase A: scores into registers; single f32 buffer, 2 barriers/segment ----
#pragma unroll
    for (int sgi = 0; sgi < SEGS; sgi++) {
        int j0 = sgi * 512;
#pragma unroll
        for (int tt = 0; tt < 2; tt++) {
            int t = w + tt * 16;
            int jt = j0 + t * 16;
            if (jt < jlen) {
                f32x4 acc = {0.f, 0.f, 0.f, 0.f};
                const bf16* kp = kbase + (size_t)(jt + lane16) * HD + quad * 8;
#pragma unroll
                for (int kc = 0; kc < 4; kc++) {
                    bf16x8 b = *(const bf16x8*)(kp + kc * 32);
                    acc = __builtin_amdgcn_mfma_f32_16x16x32_bf16(afrag[kc], b, acc, 0, 0, 0);
                }
                if (jt + 15 > r0) {  // diagonal tile: apply causal mask
                    int jj = jt + lane16;
#pragma unroll
                    for (int r = 0; r < 4; r++) {
                        int rowi = quad * 4 + r;
                        float v = acc[r];
                        if (jj > r0 + rowi) v = -1e30f;
                        buf[rowi][t * 16 + lane16] = v;
                    }
                } else {
#pragma unroll
                    for (int r = 0; r < 4; r++) buf[quad * 4 + r][t * 16 + lane16] = acc[r];
                }
            }
        }
        __syncthreads();
#pragma unroll
        for (int part = 0; part < 2; part++) {
            float4 fq = *(const float4*)&buf[w][part * 256 + l * 4];
            if (sgi == SEGS - 1) {
                int jb = j0 + part * 256 + l * 4;
                xr[sgi * 4 + part * 2 + 0] =
                    (f32x2){(jb + 0 < jlen) ? fq.x : -1e30f, (jb + 1 < jlen) ? fq.y : -1e30f};
                xr[sgi * 4 + part * 2 + 1] =
                    (f32x2){(jb + 2 < jlen) ? fq.z : -1e30f, (jb + 3 < jlen) ? fq.w : -1e30f};
            } else {
                xr[sgi * 4 + part * 2 + 0] = (f32x2){fq.x, fq.y};
                xr[sgi * 4 + part * 2 + 1] = (f32x2){fq.z, fq.w};
            }
        }
        __syncthreads();  // protect buffer before next segment's writes
    }

    float* arow = attn + ((size_t)h * S + (r0 + w)) * S;

    // ---- Phase E (early; tau-independent): zero-fill strictly-upper region; drains under B ----
    {
        f32x4 z4 = {0.f, 0.f, 0.f, 0.f};
        for (int j = SEGS * 512 + l * 4; j < S; j += 256) nt_store4(z4, &arow[j]);
    }

    // ---- Phase B: entmax-1.5 tau: 3 active-set steps + 4 Newton polish ----
    const f32x2 z2 = {0.f, 0.f};
    float mx = -1e30f;
#pragma unroll
    for (int c = 0; c < NREG2; c++) mx = fmaxf(mx, fmaxf(xr[c][0], xr[c][1]));
    float m = wave_fmax(mx);
    float taulo = m - 1.0f;
    float tauhi = m - 0.02209709f;  // m - (1/2048)^0.5: tau* <= this for all d<=2048
    float tau = taulo;

#pragma unroll 1
    for (int it = 0; it < AS_ITERS; it++) {
        f32x2 tvi = {tau, tau};
        f32x2 b1a = z2, b1b = z2, b2a = z2, b2b = z2, cna = z2, cnb = z2;
#pragma unroll
        for (int c = 0; c < NREG2; c += 2) {
            f32x2 t0 = __builtin_elementwise_max(xr[c] - tvi, z2);
            b2a += t0 * t0; b1a += t0;
            cna += (f32x2){t0[0] > 0.f ? 1.f : 0.f, t0[1] > 0.f ? 1.f : 0.f};
            f32x2 t1 = __builtin_elementwise_max(xr[c + 1] - tvi, z2);
            b2b += t1 * t1; b1b += t1;
            cnb += (f32x2){t1[0] > 0.f ? 1.f : 0.f, t1[1] > 0.f ? 1.f : 0.f};
        }
        f32x2 s1 = b1a + b1b, s2 = b2a + b2b, sc = cna + cnb;
        float B1 = wave_sum(s1[0] + s1[1]);
        float B2 = wave_sum(s2[0] + s2[1]);
        float n = wave_sum(sc[0] + sc[1]);
        // exact root of the quadratic on the current support: n*d^2 - 2*B1*d + (B2-1) = 0
        float disc = fmaxf(B1 * B1 - n * (B2 - 1.0f), 0.f);
        tau += (B1 - __builtin_sqrtf(disc)) / fmaxf(n, 1.0f);
        tau = fminf(fmaxf(tau, taulo), tauhi);
    }
#pragma unroll 1
    for (int it = 0; it < NW_ITERS; it++) {
        f32x2 tvi = {tau, tau};
        f32x2 fa = z2, fb = z2, ga = z2, gb = z2;
#pragma unroll
        for (int c = 0; c < NREG2; c += 2) {
            f32x2 t0 = __builtin_elementwise_max(xr[c] - tvi, z2);
            fa += t0 * t0; ga += t0;
            f32x2 t1 = __builtin_elementwise_max(xr[c + 1] - tvi, z2);
            fb += t1 * t1; gb += t1;
        }
        f32x2 fv = fa + fb, gv = ga + gb;
        float f = wave_sum(fv[0] + fv[1]);
        float g = wave_sum(gv[0] + gv[1]);
        tau += (f - 1.0f) / (2.0f * g + 1e-20f);  // monotone on convex f, both sides
        tau = fminf(fmaxf(tau, taulo), tauhi);
    }

    f32x2 tv = {tau, tau};
    float inv;
    {
        f32x2 sa = z2, sbv = z2;
#pragma unroll
        for (int c = 0; c < NREG2; c += 2) {
            f32x2 t0 = __builtin_elementwise_max(xr[c] - tv, z2);
            sa += t0 * t0;
            f32x2 t1 = __builtin_elementwise_max(xr[c + 1] - tv, z2);
            sbv += t1 * t1;
        }
        f32x2 sv = sa + sbv;
        float ssum = wave_sum(sv[0] + sv[1]);
        inv = 1.0f / ssum;
    }

    // ---- Phase C: P f32 -> attn global (fused; xr dies here) + P bf16 -> LDS
    //      (ping-pong halves), P.V MFMA; 1 barrier/segment ----
    int jt_o = (w & 7) * 16;
    int kh = (w >> 3) * 256;
    f32x4 acc_o = {0.f, 0.f, 0.f, 0.f};
    f32x2 inv2 = {inv, inv};

#pragma unroll
    for (int sgi = 0; sgi < SEGS; sgi++) {
        int j0 = sgi * 512;
        bf16 (*pb)[BROW] = (bf16(*)[BROW])(&buf[0][0]) + (sgi & 1) * 16;
#pragma unroll
        for (int part = 0; part < 2; part++) {
            f32x2 ta = __builtin_elementwise_max(xr[sgi * 4 + part * 2 + 0] - tv, z2);
            f32x2 tb = __builtin_elementwise_max(xr[sgi * 4 + part * 2 + 1] - tv, z2);
            f32x2 pa = (ta * ta) * inv2;
            f32x2 pb2 = (tb * tb) * inv2;
            f32x4 pv = {pa[0], pa[1], pb2[0], pb2[1]};
            nt_store4(pv, &arow[j0 + part * 256 + l * 4]);
            bf16x4 pbv;
            pbv[0] = (bf16)pv[0]; pbv[1] = (bf16)pv[1];
            pbv[2] = (bf16)pv[2]; pbv[3] = (bf16)pv[3];
            *(bf16x4*)&pb[w][part * 256 + l * 4] = pbv;
        }
        __syncthreads();
#pragma unroll
        for (int ks = 0; ks < 8; ks++) {
            int kk = kh + ks * 32;
            bf16x8 a = *(const bf16x8*)&pb[lane16][kk + quad * 8];
            bf16x8 b = *(const bf16x8*)(vbase + (size_t)(jt_o + lane16) * S + j0 + kk + quad * 8);
            acc_o = __builtin_amdgcn_mfma_f32_16x16x32_bf16(a, b, acc_o, 0, 0, 0);
        }
        // no trailing barrier: next segment writes the other half; its barrier orders reuse
    }

    // ---- Phase D: combine K-halves, write O ----
    __syncthreads();  // all P.V MFMA reads done before buf reuse as f32
    if (w >= 8) {
#pragma unroll
        for (int r = 0; r < 4; r++) buf[w - 8][l * 4 + r] = acc_o[r];
    }
    __syncthreads();
    if (w < 8) {
        bf16* op = o + (size_t)(r0 + quad * 4) * DM + h * HD + jt_o + lane16;
#pragma unroll
        for (int r = 0; r < 4; r++) {
            float v = acc_o[r] + buf[w][l * 4 + r];
            op[(size_t)r * DM] = (bf16)v;
        }
    }
}

// Persistent workgroups: 512 blocks (2/CU), each runs one item of every causal class
// {4,3,2,1} -> exactly 10 segments per block, perfectly uniform load.
// __launch_bounds__(1024, 8): VGPR clamp -> xr spills to L3-resident scratch, but
// 2 blocks/CU co-reside (80% occ) — measured fastest config (R2: 220 us).
__global__ __launch_bounds__(1024, 8) void attn_av_all(const bf16* __restrict__ qs,
                                                       const bf16* __restrict__ kb,
                                                       const bf16* __restrict__ vT,
                                                       float* __restrict__ attn,
                                                       bf16* __restrict__ o) {
    __shared__ float buf[16][BROW];  // ~35 KB -> 2 blocks/CU fit LDS
    int b = blockIdx.x;  // 0..511
    int h = b & 15;
    int qh = b >> 4;     // 0..31
    attn_body<4>(qs, kb, vT, attn, o, (96 + qh) * 16, h, buf);
    __syncthreads();
    attn_body<3>(qs, kb, vT, attn, o, (64 + qh) * 16, h, buf);
    __syncthreads();
    attn_body<2>(qs, kb, vT, attn, o, (32 + qh) * 16, h, buf);
    __syncthreads();
    attn_body<1>(qs, kb, vT, attn, o, qh * 16, h, buf);
}

extern "C" void kernel_launch(void* const* d_in, const int* in_sizes, int n_in,
                              void* d_out, int out_size, void* d_ws, size_t ws_size,
                              hipStream_t stream) {
    const float* hidden = (const float*)d_in[0];
    const float* cosb   = (const float*)d_in[1];
    const float* sinb   = (const float*)d_in[2];
    const float* wq     = (const float*)d_in[3];
    const float* wk     = (const float*)d_in[4];
    const float* wv     = (const float*)d_in[5];
    const float* wo     = (const float*)d_in[6];
    char* ws = (char*)d_ws;
    bf16*  bf_hidden = (bf16*)(ws);                    // 8 MB; reused as O bf16 later
    bf16*  bf_wqkv   = (bf16*)(ws + 8388608);          // 12 MB
    bf16*  bf_wo     = (bf16*)(ws + 20971520);         // 8 MB
    float* qkv_raw   = (float*)(ws + 29360128);        // 24 MB
    bf16*  qsb       = (bf16*)(ws + 54525952);         // 8 MB  [H][S][HD]
    bf16*  kbb       = (bf16*)(ws + 62914560);         // 2 MB  [4][S][HD]
    bf16*  vTb       = (bf16*)(ws + 65011712);         // 2 MB  [4][HD][S]
    float* out  = (float*)d_out;
    float* attn = out + 4194304;

    cvt_all<<<dim3(14336), 256, 0, stream>>>(hidden, wq, wk, wv, wo, bf_hidden, bf_wqkv, bf_wo);

    // QKV projection: [2048 x 2048] @ [3072 x 2048]^T
    gemm128_bt<<<dim3(16, 24), 256, 0, stream>>>(bf_hidden, bf_wqkv, qkv_raw, NQKV, DM);

    rope_qk<<<dim3(10, S), 256, 0, stream>>>(qkv_raw, cosb, sinb, qsb, kbb);
    vtrans<<<dim3(32, 8), 256, 0, stream>>>(qkv_raw, vTb);

    // fused scores + entmax + P.V + attn write  (512 persistent blocks, 2/CU)
    attn_av_all<<<dim3(512), 1024, 0, stream>>>(qsb, kbb, vTb, attn, bf_hidden);

    // out = O @ wo^T
    gemm128_bt<<<dim3(16, 16), 256, 0, stream>>>(bf_hidden, bf_wo, out, DM, DM);
}

// Round 9
// 567.084 us; speedup vs baseline: 1.0987x; 1.0348x over previous
//
#include <hip/hip_runtime.h>

typedef __bf16 bf16;
typedef __bf16 bf16x4 __attribute__((ext_vector_type(4)));
typedef __bf16 bf16x8 __attribute__((ext_vector_type(8)));
typedef float f32x4 __attribute__((ext_vector_type(4)));
typedef float f32x2 __attribute__((ext_vector_type(2)));

#define S 2048
#define DM 2048
#define HD 128
#define H 16
#define NQKV 3072
#define AS_ITERS 3
#define NW_ITERS 3
#define BROW 556  // f32 row stride of attn LDS buf; 556%32=12 -> no bank conflicts (R3-R8)

__device__ __forceinline__ void gl2lds16(const void* g, void* l) {
    __builtin_amdgcn_global_load_lds(
        (const __attribute__((address_space(1))) void*)g,
        (__attribute__((address_space(3))) void*)l, 16, 0, 0);
}

__device__ __forceinline__ void nt_store4(f32x4 v, float* p) {
    __builtin_nontemporal_store(v, (f32x4*)p);
}

// ---------------- DPP-based wave(64) reductions ----------------
template <int CTRL, int RM>
__device__ __forceinline__ float dpp_zero(float x) {
    return __builtin_bit_cast(float, __builtin_amdgcn_update_dpp(
        0, __builtin_bit_cast(int, x), CTRL, RM, 0xf, false));
}
template <int CTRL, int RM>
__device__ __forceinline__ float dpp_self(float x) {
    int xi = __builtin_bit_cast(int, x);
    return __builtin_bit_cast(float, __builtin_amdgcn_update_dpp(xi, xi, CTRL, RM, 0xf, false));
}
__device__ __forceinline__ float wave_bcast63(float x) {
    return __builtin_bit_cast(float, __builtin_amdgcn_readlane(__builtin_bit_cast(int, x), 63));
}
__device__ __forceinline__ float wave_sum(float x) {
    x += dpp_zero<0x111, 0xf>(x);
    x += dpp_zero<0x112, 0xf>(x);
    x += dpp_zero<0x114, 0xf>(x);
    x += dpp_zero<0x118, 0xf>(x);
    x += dpp_zero<0x142, 0xa>(x);
    x += dpp_zero<0x143, 0xc>(x);
    return wave_bcast63(x);
}
__device__ __forceinline__ float wave_fmax(float x) {
    x = fmaxf(x, dpp_self<0x111, 0xf>(x));
    x = fmaxf(x, dpp_self<0x112, 0xf>(x));
    x = fmaxf(x, dpp_self<0x114, 0xf>(x));
    x = fmaxf(x, dpp_self<0x118, 0xf>(x));
    x = fmaxf(x, dpp_self<0x142, 0xa>(x));
    x = fmaxf(x, dpp_self<0x143, 0xc>(x));
    return wave_bcast63(x);
}

// ---------------- fused fp32 -> bf16 convert for all 5 inputs (float4 granules) ----------------
__global__ void cvt_all(const float* __restrict__ hid, const float* __restrict__ wq,
                        const float* __restrict__ wk, const float* __restrict__ wv,
                        const float* __restrict__ wo, bf16* __restrict__ bh,
                        bf16* __restrict__ bqkv, bf16* __restrict__ bwo) {
    int i = blockIdx.x * blockDim.x + threadIdx.x;
    const float* src;
    bf16* dst;
    int off;
    if (i < 1048576) { src = hid; dst = bh; off = i; }
    else if (i < 2097152) { src = wq; dst = bqkv; off = i - 1048576; }
    else if (i < 2359296) { src = wk; dst = bqkv + 2048 * 2048; off = i - 2097152; }
    else if (i < 2621440) { src = wv; dst = bqkv + 2048 * 2048 + 512 * 2048; off = i - 2359296; }
    else { src = wo; dst = bwo; off = i - 2621440; }
    float4 f = ((const float4*)src)[off];
    bf16x4 o;
    o[0] = (bf16)f.x; o[1] = (bf16)f.y; o[2] = (bf16)f.z; o[3] = (bf16)f.w;
    ((bf16x4*)dst)[off] = o;
}

// ---------------- QKV GEMM (64x128, dbuf) with FUSED RoPE + V-transpose epilogue --------
// C[m=s][n=col] = hidden . wqkv^T. by<16 -> Q head by; 16<=by<20 -> K kv=by-16; by>=20 ->
// V (y0=(by-20)*128). BN=128 aligns tiles to head boundaries so the RoPE pair (d, d+-64)
// is inside the tile. Epilogue stages 32-row halves of C in LDS (pad 129: conflict-free
// column reads for V-transpose), then writes qs/kb (RoPE'd, coalesced in d) or vT
// (transposed, coalesced in s). Eliminates rope_qk, vtrans, and the 24 MB qkv_raw.
__global__ __launch_bounds__(256) void gemm_qkv_rope(const bf16* __restrict__ A,
                                                     const bf16* __restrict__ B,
                                                     const float* __restrict__ cosb,
                                                     const float* __restrict__ sinb,
                                                     bf16* __restrict__ qs,
                                                     bf16* __restrict__ kb,
                                                     bf16* __restrict__ vT) {
    constexpr int BM = 64, BN = 128, K = DM;
    __shared__ bf16 As[2][BM * 32];
    __shared__ bf16 Bs[2][BN * 32];
    __shared__ float ct[32][129];
    int m0 = blockIdx.x * BM;
    int by = blockIdx.y;
    int n0 = by * BN;
    int t = threadIdx.x;
    int l = t & 63, w = t >> 6;
    int lane16 = l & 15, quad = l >> 4;

    const bf16* Abase = A + (size_t)m0 * K;
    const bf16* Bbase = B + (size_t)n0 * K;

    constexpr int MI = BM / 32, NI = BN / 32;
    int wm = (w & 1) * (BM / 2), wn = (w >> 1) * (BN / 2);
    f32x4 acc[MI][NI];
#pragma unroll
    for (int i = 0; i < MI; i++)
#pragma unroll
        for (int j = 0; j < NI; j++) acc[i][j] = (f32x4){0.f, 0.f, 0.f, 0.f};

    constexpr int AG = BM * 4;
    constexpr int BG = BN * 4;

    auto stage = [&](int sel, int k0) {
#pragma unroll
        for (int it = 0; it < AG / 256; it++) {
            int c = it * 256 + t;
            gl2lds16(Abase + (size_t)(c >> 2) * K + k0 + (c & 3) * 8, &As[sel][(c - l) * 8]);
        }
#pragma unroll
        for (int it = 0; it < BG / 256; it++) {
            int c = it * 256 + t;
            gl2lds16(Bbase + (size_t)(c >> 2) * K + k0 + (c & 3) * 8, &Bs[sel][(c - l) * 8]);
        }
    };

    stage(0, 0);
    __syncthreads();
    int cur = 0;
    for (int k0 = 0; k0 < K; k0 += 32) {
        if (k0 + 32 < K) stage(cur ^ 1, k0 + 32);
        bf16x8 af[MI], bfr[NI];
#pragma unroll
        for (int i = 0; i < MI; i++)
            af[i] = *(const bf16x8*)&As[cur][(wm + i * 16 + lane16) * 32 + quad * 8];
#pragma unroll
        for (int j = 0; j < NI; j++)
            bfr[j] = *(const bf16x8*)&Bs[cur][(wn + j * 16 + lane16) * 32 + quad * 8];
#pragma unroll
        for (int i = 0; i < MI; i++)
#pragma unroll
            for (int j = 0; j < NI; j++)
                acc[i][j] = __builtin_amdgcn_mfma_f32_16x16x32_bf16(af[i], bfr[j], acc[i][j], 0, 0, 0);
        __syncthreads();
        cur ^= 1;
    }

    // ---- epilogue: two 32-row halves through LDS ----
#pragma unroll
    for (int half = 0; half < 2; half++) {
        if ((w & 1) == half) {  // waves whose rows are [half*32, half*32+32)
#pragma unroll
            for (int i = 0; i < MI; i++)
#pragma unroll
                for (int j = 0; j < NI; j++)
#pragma unroll
                    for (int r = 0; r < 4; r++)
                        ct[i * 16 + quad * 4 + r][wn + j * 16 + lane16] = acc[i][j][r];
        }
        __syncthreads();
        if (by < 20) {
            // q (by<16) or k: RoPE. 32x128 elems, 16/thread; lanes -> consecutive d.
#pragma unroll
            for (int it = 0; it < 16; it++) {
                int idx = it * 256 + t;
                int row = idx >> 7, d = idx & 127;
                int s = m0 + half * 32 + row;
                float v = ct[row][d];
                float other = ct[row][(d < 64) ? (d + 64) : (d - 64)];
                float c = cosb[s * HD + d], sn = sinb[s * HD + d];
                float rot = (d < 64) ? -other : other;
                float o = v * c + rot * sn;
                if (by < 16)
                    qs[((size_t)by * S + s) * HD + d] = (bf16)(o * 0.04419417382415922f);
                else
                    kb[((size_t)(by - 16) * S + s) * HD + d] = (bf16)o;
            }
        } else {
            // V: transposed write, coalesced in s. Column reads conflict-free (pad 129).
            int y0 = (by - 20) * 128;
#pragma unroll
            for (int it = 0; it < 16; it++) {
                int idx = it * 256 + t;
                int y = idx >> 5, ss = idx & 31;
                vT[(size_t)(y0 + y) * S + m0 + half * 32 + ss] = (bf16)ct[ss][y];
            }
        }
        __syncthreads();
    }
}

// ---------------- WO GEMM: 64x128 dbuf (2/CU balanced at grid 32x16) ----------------
template <int BM, int BN>
__global__ __launch_bounds__(256) void gemm_bt(const bf16* __restrict__ A,
                                               const bf16* __restrict__ B,
                                               float* __restrict__ C, int Ndim, int K) {
    __shared__ bf16 As[2][BM * 32];
    __shared__ bf16 Bs[2][BN * 32];
    int m0 = blockIdx.x * BM, n0 = blockIdx.y * BN;
    int t = threadIdx.x;
    int l = t & 63, w = t >> 6;
    int lane16 = l & 15, quad = l >> 4;

    const bf16* Abase = A + (size_t)m0 * K;
    const bf16* Bbase = B + (size_t)n0 * K;

    constexpr int MI = BM / 32, NI = BN / 32;
    int wm = (w & 1) * (BM / 2), wn = (w >> 1) * (BN / 2);
    f32x4 acc[MI][NI];
#pragma unroll
    for (int i = 0; i < MI; i++)
#pragma unroll
        for (int j = 0; j < NI; j++) acc[i][j] = (f32x4){0.f, 0.f, 0.f, 0.f};

    constexpr int AG = BM * 4;
    constexpr int BG = BN * 4;

    auto stage = [&](int sel, int k0) {
#pragma unroll
        for (int it = 0; it < AG / 256; it++) {
            int c = it * 256 + t;
            gl2lds16(Abase + (size_t)(c >> 2) * K + k0 + (c & 3) * 8, &As[sel][(c - l) * 8]);
        }
#pragma unroll
        for (int it = 0; it < BG / 256; it++) {
            int c = it * 256 + t;
            gl2lds16(Bbase + (size_t)(c >> 2) * K + k0 + (c & 3) * 8, &Bs[sel][(c - l) * 8]);
        }
    };

    stage(0, 0);
    __syncthreads();
    int cur = 0;
    for (int k0 = 0; k0 < K; k0 += 32) {
        if (k0 + 32 < K) stage(cur ^ 1, k0 + 32);
        bf16x8 af[MI], bfr[NI];
#pragma unroll
        for (int i = 0; i < MI; i++)
            af[i] = *(const bf16x8*)&As[cur][(wm + i * 16 + lane16) * 32 + quad * 8];
#pragma unroll
        for (int j = 0; j < NI; j++)
            bfr[j] = *(const bf16x8*)&Bs[cur][(wn + j * 16 + lane16) * 32 + quad * 8];
#pragma unroll
        for (int i = 0; i < MI; i++)
#pragma unroll
            for (int j = 0; j < NI; j++)
                acc[i][j] = __builtin_amdgcn_mfma_f32_16x16x32_bf16(af[i], bfr[j], acc[i][j], 0, 0, 0);
        __syncthreads();
        cur ^= 1;
    }
#pragma unroll
    for (int i = 0; i < MI; i++)
#pragma unroll
        for (int j = 0; j < NI; j++) {
            float* cp = C + (size_t)(m0 + wm + i * 16 + quad * 4) * Ndim + n0 + wn + j * 16 + lane16;
#pragma unroll
            for (int r = 0; r < 4; r++) cp[(size_t)r * Ndim] = acc[i][j][r];
        }
}

// ------- fused: scores (MFMA) + causal mask + entmax tau + P.V (MFMA) + attn write -------
// Frozen R8 structure (best measured: 214 us): 16-wave blocks, launch_bounds(1024,8)
// (VGPR clamp -> xr spills to L3-resident scratch, but 2 blocks/CU = 80% occ wins),
// tau = 3 active-set + 3 Newton polish (8 full-row passes), attn store fused in Phase C.
template <int SEGS>
__device__ __forceinline__ void attn_body(const bf16* __restrict__ qs, const bf16* __restrict__ kb,
                                          const bf16* __restrict__ vT, float* __restrict__ attn,
                                          bf16* __restrict__ o, int r0, int h,
                                          float (&buf)[16][BROW]) {
    constexpr int NREG2 = SEGS * 4;  // f32x2 regs per lane (= SEGS*8 scores)
    int jlen = r0 + 16;
    int l = threadIdx.x & 63;
    int w = threadIdx.x >> 6;  // 0..15
    int lane16 = l & 15, quad = l >> 4;

    const bf16* qrow = qs + ((size_t)h * S + (r0 + lane16)) * HD + quad * 8;
    bf16x8 afrag[4];
#pragma unroll
    for (int kc = 0; kc < 4; kc++) afrag[kc] = *(const bf16x8*)(qrow + kc * 32);

    const bf16* kbase = kb + (size_t)(h >> 2) * S * HD;
    const bf16* vbase = vT + (size_t)(h >> 2) * HD * S;
    f32x2 xr[NREG2];

    // ---- Phase A: scores into registers; single f32 buffer, 2 barriers/segment ----
#pragma unroll
    for (int sgi = 0; sgi < SEGS; sgi++) {
        int j0 = sgi * 512;
#pragma unroll
        for (int tt = 0; tt < 2; tt++) {
            int t = w + tt * 16;
            int jt = j0 + t * 16;
            if (jt < jlen) {
                f32x4 acc = {0.f, 0.f, 0.f, 0.f};
                const bf16* kp = kbase + (size_t)(jt + lane16) * HD + quad * 8;
#pragma unroll
                for (int kc = 0; kc < 4; kc++) {
                    bf16x8 b = *(const bf16x8*)(kp + kc * 32);
                    acc = __builtin_amdgcn_mfma_f32_16x16x32_bf16(afrag[kc], b, acc, 0, 0, 0);
                }
                if (jt + 15 > r0) {  // diagonal tile: apply causal mask
                    int jj = jt + lane16;
#pragma unroll
                    for (int r = 0; r < 4; r++) {
                        int rowi = quad * 4 + r;
                        float v = acc[r];
                        if (jj > r0 + rowi) v = -1e30f;
                        buf[rowi][t * 16 + lane16] = v;
                    }
                } else {
#pragma unroll
                    for (int r = 0; r < 4; r++) buf[quad * 4 + r][t * 16 + lane16] = acc[r];
                }
            }
        }
        __syncthreads();
#pragma unroll
        for (int part = 0; part < 2; part++) {
            float4 fq = *(const float4*)&buf[w][part * 256 + l * 4];
            if (sgi == SEGS - 1) {
                int jb = j0 + part * 256 + l * 4;
                xr[sgi * 4 + part * 2 + 0] =
                    (f32x2){(jb + 0 < jlen) ? fq.x : -1e30f, (jb + 1 < jlen) ? fq.y : -1e30f};
                xr[sgi * 4 + part * 2 + 1] =
                    (f32x2){(jb + 2 < jlen) ? fq.z : -1e30f, (jb + 3 < jlen) ? fq.w : -1e30f};
            } else {
                xr[sgi * 4 + part * 2 + 0] = (f32x2){fq.x, fq.y};
                xr[sgi * 4 + part * 2 + 1] = (f32x2){fq.z, fq.w};
            }
        }
        __syncthreads();
    }

    float* arow = attn + ((size_t)h * S + (r0 + w)) * S;

    // ---- Phase E (early; tau-independent): zero-fill strictly-upper region ----
    {
        f32x4 z4 = {0.f, 0.f, 0.f, 0.f};
        for (int j = SEGS * 512 + l * 4; j < S; j += 256) nt_store4(z4, &arow[j]);
    }

    // ---- Phase B: entmax-1.5 tau: 3 active-set steps + 3 Newton polish ----
    const f32x2 z2 = {0.f, 0.f};
    float mx = -1e30f;
#pragma unroll
    for (int c = 0; c < NREG2; c++) mx = fmaxf(mx, fmaxf(xr[c][0], xr[c][1]));
    float m = wave_fmax(mx);
    float taulo = m - 1.0f;
    float tauhi = m - 0.02209709f;  // m - (1/2048)^0.5
    float tau = taulo;

#pragma unroll 1
    for (int it = 0; it < AS_ITERS; it++) {
        f32x2 tvi = {tau, tau};
        f32x2 b1a = z2, b1b = z2, b2a = z2, b2b = z2, cna = z2, cnb = z2;
#pragma unroll
        for (int c = 0; c < NREG2; c += 2) {
            f32x2 t0 = __builtin_elementwise_max(xr[c] - tvi, z2);
            b2a += t0 * t0; b1a += t0;
            cna += (f32x2){t0[0] > 0.f ? 1.f : 0.f, t0[1] > 0.f ? 1.f : 0.f};
            f32x2 t1 = __builtin_elementwise_max(xr[c + 1] - tvi, z2);
            b2b += t1 * t1; b1b += t1;
            cnb += (f32x2){t1[0] > 0.f ? 1.f : 0.f, t1[1] > 0.f ? 1.f : 0.f};
        }
        f32x2 s1 = b1a + b1b, s2 = b2a + b2b, sc = cna + cnb;
        float B1 = wave_sum(s1[0] + s1[1]);
        float B2 = wave_sum(s2[0] + s2[1]);
        float n = wave_sum(sc[0] + sc[1]);
        float disc = fmaxf(B1 * B1 - n * (B2 - 1.0f), 0.f);
        tau += (B1 - __builtin_sqrtf(disc)) / fmaxf(n, 1.0f);
        tau = fminf(fmaxf(tau, taulo), tauhi);
    }
#pragma unroll 1
    for (int it = 0; it < NW_ITERS; it++) {
        f32x2 tvi = {tau, tau};
        f32x2 fa = z2, fb = z2, ga = z2, gb = z2;
#pragma unroll
        for (int c = 0; c < NREG2; c += 2) {
            f32x2 t0 = __builtin_elementwise_max(xr[c] - tvi, z2);
            fa += t0 * t0; ga += t0;
            f32x2 t1 = __builtin_elementwise_max(xr[c + 1] - tvi, z2);
            fb += t1 * t1; gb += t1;
        }
        f32x2 fv = fa + fb, gv = ga + gb;
        float f = wave_sum(fv[0] + fv[1]);
        float g = wave_sum(gv[0] + gv[1]);
        tau += (f - 1.0f) / (2.0f * g + 1e-20f);
        tau = fminf(fmaxf(tau, taulo), tauhi);
    }

    f32x2 tv = {tau, tau};
    float inv;
    {
        f32x2 sa = z2, sbv = z2;
#pragma unroll
        for (int c = 0; c < NREG2; c += 2) {
            f32x2 t0 = __builtin_elementwise_max(xr[c] - tv, z2);
            sa += t0 * t0;
            f32x2 t1 = __builtin_elementwise_max(xr[c + 1] - tv, z2);
            sbv += t1 * t1;
        }
        f32x2 sv = sa + sbv;
        float ssum = wave_sum(sv[0] + sv[1]);
        inv = 1.0f / ssum;
    }

    // ---- Phase C: P f32 -> attn global (fused; xr dies here) + P bf16 -> LDS
    //      (ping-pong halves), P.V MFMA; 1 barrier/segment ----
    int jt_o = (w & 7) * 16;
    int kh = (w >> 3) * 256;
    f32x4 acc_o = {0.f, 0.f, 0.f, 0.f};
    f32x2 inv2 = {inv, inv};

#pragma unroll
    for (int sgi = 0; sgi < SEGS; sgi++) {
        int j0 = sgi * 512;
        bf16 (*pb)[BROW] = (bf16(*)[BROW])(&buf[0][0]) + (sgi & 1) * 16;
#pragma unroll
        for (int part = 0; part < 2; part++) {
            f32x2 ta = __builtin_elementwise_max(xr[sgi * 4 + part * 2 + 0] - tv, z2);
            f32x2 tb = __builtin_elementwise_max(xr[sgi * 4 + part * 2 + 1] - tv, z2);
            f32x2 pa = (ta * ta) * inv2;
            f32x2 pb2 = (tb * tb) * inv2;
            f32x4 pv = {pa[0], pa[1], pb2[0], pb2[1]};
            nt_store4(pv, &arow[j0 + part * 256 + l * 4]);
            bf16x4 pbv;
            pbv[0] = (bf16)pv[0]; pbv[1] = (bf16)pv[1];
            pbv[2] = (bf16)pv[2]; pbv[3] = (bf16)pv[3];
            *(bf16x4*)&pb[w][part * 256 + l * 4] = pbv;
        }
        __syncthreads();
#pragma unroll
        for (int ks = 0; ks < 8; ks++) {
            int kk = kh + ks * 32;
            bf16x8 a = *(const bf16x8*)&pb[lane16][kk + quad * 8];
            bf16x8 b = *(const bf16x8*)(vbase + (size_t)(jt_o + lane16) * S + j0 + kk + quad * 8);
            acc_o = __builtin_amdgcn_mfma_f32_16x16x32_bf16(a, b, acc_o, 0, 0, 0);
        }
    }

    // ---- Phase D: combine K-halves, write O ----
    __syncthreads();
    if (w >= 8) {
#pragma unroll
        for (int r = 0; r < 4; r++) buf[w - 8][l * 4 + r] = acc_o[r];
    }
    __syncthreads();
    if (w < 8) {
        bf16* op = o + (size_t)(r0 + quad * 4) * DM + h * HD + jt_o + lane16;
#pragma unroll
        for (int r = 0; r < 4; r++) {
            float v = acc_o[r] + buf[w][l * 4 + r];
            op[(size_t)r * DM] = (bf16)v;
        }
    }
}

// 512 persistent blocks (2/CU), classes {4,3,2,1} = 10 segments/block, uniform.
__global__ __launch_bounds__(1024, 8) void attn_av_all(const bf16* __restrict__ qs,
                                                       const bf16* __restrict__ kb,
                                                       const bf16* __restrict__ vT,
                                                       float* __restrict__ attn,
                                                       bf16* __restrict__ o) {
    __shared__ float buf[16][BROW];
    int b = blockIdx.x;
    int h = b & 15;
    int qh = b >> 4;
    attn_body<4>(qs, kb, vT, attn, o, (96 + qh) * 16, h, buf);
    __syncthreads();
    attn_body<3>(qs, kb, vT, attn, o, (64 + qh) * 16, h, buf);
    __syncthreads();
    attn_body<2>(qs, kb, vT, attn, o, (32 + qh) * 16, h, buf);
    __syncthreads();
    attn_body<1>(qs, kb, vT, attn, o, qh * 16, h, buf);
}

extern "C" void kernel_launch(void* const* d_in, const int* in_sizes, int n_in,
                              void* d_out, int out_size, void* d_ws, size_t ws_size,
                              hipStream_t stream) {
    const float* hidden = (const float*)d_in[0];
    const float* cosb   = (const float*)d_in[1];
    const float* sinb   = (const float*)d_in[2];
    const float* wq     = (const float*)d_in[3];
    const float* wk     = (const float*)d_in[4];
    const float* wv     = (const float*)d_in[5];
    const float* wo     = (const float*)d_in[6];
    char* ws = (char*)d_ws;
    bf16*  bf_hidden = (bf16*)(ws);                    // 8 MB; reused as O bf16 later
    bf16*  bf_wqkv   = (bf16*)(ws + 8388608);          // 12 MB
    bf16*  bf_wo     = (bf16*)(ws + 20971520);         // 8 MB
    bf16*  qsb       = (bf16*)(ws + 29360128);         // 8 MB  [H][S][HD]
    bf16*  kbb       = (bf16*)(ws + 37748736);         // 2 MB  [4][S][HD]
    bf16*  vTb       = (bf16*)(ws + 39845888);         // 2 MB  [4][HD][S]
    float* out  = (float*)d_out;
    float* attn = out + 4194304;

    cvt_all<<<dim3(14336), 256, 0, stream>>>(hidden, wq, wk, wv, wo, bf_hidden, bf_wqkv, bf_wo);

    // QKV projection with fused RoPE + V-transpose epilogue (768 blocks = 3/CU balanced)
    gemm_qkv_rope<<<dim3(32, 24), 256, 0, stream>>>(bf_hidden, bf_wqkv, cosb, sinb,
                                                    qsb, kbb, vTb);

    // fused scores + entmax + P.V + attn write  (512 persistent blocks, 2/CU)
    attn_av_all<<<dim3(512), 1024, 0, stream>>>(qsb, kbb, vTb, attn, bf_hidden);

    // out = O @ wo^T  (512 blocks = 2/CU balanced)
    gemm_bt<64, 128><<<dim3(32, 16), 256, 0, stream>>>(bf_hidden, bf_wo, out, DM, DM);
}

// Round 10
// 564.474 us; speedup vs baseline: 1.1038x; 1.0046x over previous
//
#include <hip/hip_runtime.h>

typedef __bf16 bf16;
typedef __bf16 bf16x4 __attribute__((ext_vector_type(4)));
typedef __bf16 bf16x8 __attribute__((ext_vector_type(8)));
typedef float f32x4 __attribute__((ext_vector_type(4)));
typedef float f32x2 __attribute__((ext_vector_type(2)));
typedef _Float16 f16x8 __attribute__((ext_vector_type(8)));

#define S 2048
#define DM 2048
#define HD 128
#define H 16
#define NQKV 3072
#define AS_ITERS 3
#define NW_ITERS 3
#define SROW 2056         // f16 row stride: 4112 B -> 4-bank shift/row; b128 row reads conflict-free
#define MASKV -30000.0f   // f16-representable mask value

__device__ __forceinline__ void gl2lds16(const void* g, void* l) {
    __builtin_amdgcn_global_load_lds(
        (const __attribute__((address_space(1))) void*)g,
        (__attribute__((address_space(3))) void*)l, 16, 0, 0);
}

__device__ __forceinline__ void nt_store4(f32x4 v, float* p) {
    __builtin_nontemporal_store(v, (f32x4*)p);
}

// ---------------- DPP-based wave(64) reductions ----------------
template <int CTRL, int RM>
__device__ __forceinline__ float dpp_zero(float x) {
    return __builtin_bit_cast(float, __builtin_amdgcn_update_dpp(
        0, __builtin_bit_cast(int, x), CTRL, RM, 0xf, false));
}
template <int CTRL, int RM>
__device__ __forceinline__ float dpp_self(float x) {
    int xi = __builtin_bit_cast(int, x);
    return __builtin_bit_cast(float, __builtin_amdgcn_update_dpp(xi, xi, CTRL, RM, 0xf, false));
}
__device__ __forceinline__ float wave_bcast63(float x) {
    return __builtin_bit_cast(float, __builtin_amdgcn_readlane(__builtin_bit_cast(int, x), 63));
}
__device__ __forceinline__ float wave_sum(float x) {
    x += dpp_zero<0x111, 0xf>(x);
    x += dpp_zero<0x112, 0xf>(x);
    x += dpp_zero<0x114, 0xf>(x);
    x += dpp_zero<0x118, 0xf>(x);
    x += dpp_zero<0x142, 0xa>(x);
    x += dpp_zero<0x143, 0xc>(x);
    return wave_bcast63(x);
}
__device__ __forceinline__ float wave_fmax(float x) {
    x = fmaxf(x, dpp_self<0x111, 0xf>(x));
    x = fmaxf(x, dpp_self<0x112, 0xf>(x));
    x = fmaxf(x, dpp_self<0x114, 0xf>(x));
    x = fmaxf(x, dpp_self<0x118, 0xf>(x));
    x = fmaxf(x, dpp_self<0x142, 0xa>(x));
    x = fmaxf(x, dpp_self<0x143, 0xc>(x));
    return wave_bcast63(x);
}

// ---------------- fused fp32 -> bf16 convert for all 5 inputs (float4 granules) ----------------
__global__ void cvt_all(const float* __restrict__ hid, const float* __restrict__ wq,
                        const float* __restrict__ wk, const float* __restrict__ wv,
                        const float* __restrict__ wo, bf16* __restrict__ bh,
                        bf16* __restrict__ bqkv, bf16* __restrict__ bwo) {
    int i = blockIdx.x * blockDim.x + threadIdx.x;
    const float* src;
    bf16* dst;
    int off;
    if (i < 1048576) { src = hid; dst = bh; off = i; }
    else if (i < 2097152) { src = wq; dst = bqkv; off = i - 1048576; }
    else if (i < 2359296) { src = wk; dst = bqkv + 2048 * 2048; off = i - 2097152; }
    else if (i < 2621440) { src = wv; dst = bqkv + 2048 * 2048 + 512 * 2048; off = i - 2359296; }
    else { src = wo; dst = bwo; off = i - 2621440; }
    float4 f = ((const float4*)src)[off];
    bf16x4 o;
    o[0] = (bf16)f.x; o[1] = (bf16)f.y; o[2] = (bf16)f.z; o[3] = (bf16)f.w;
    ((bf16x4*)dst)[off] = o;
}

// ---------------- QKV GEMM (64x128, dbuf) with FUSED RoPE + V-transpose epilogue --------
__global__ __launch_bounds__(256) void gemm_qkv_rope(const bf16* __restrict__ A,
                                                     const bf16* __restrict__ B,
                                                     const float* __restrict__ cosb,
                                                     const float* __restrict__ sinb,
                                                     bf16* __restrict__ qs,
                                                     bf16* __restrict__ kb,
                                                     bf16* __restrict__ vT) {
    constexpr int BM = 64, BN = 128, K = DM;
    __shared__ bf16 As[2][BM * 32];
    __shared__ bf16 Bs[2][BN * 32];
    __shared__ float ct[32][129];
    int m0 = blockIdx.x * BM;
    int by = blockIdx.y;
    int n0 = by * BN;
    int t = threadIdx.x;
    int l = t & 63, w = t >> 6;
    int lane16 = l & 15, quad = l >> 4;

    const bf16* Abase = A + (size_t)m0 * K;
    const bf16* Bbase = B + (size_t)n0 * K;

    constexpr int MI = BM / 32, NI = BN / 32;
    int wm = (w & 1) * (BM / 2), wn = (w >> 1) * (BN / 2);
    f32x4 acc[MI][NI];
#pragma unroll
    for (int i = 0; i < MI; i++)
#pragma unroll
        for (int j = 0; j < NI; j++) acc[i][j] = (f32x4){0.f, 0.f, 0.f, 0.f};

    constexpr int AG = BM * 4;
    constexpr int BG = BN * 4;

    auto stage = [&](int sel, int k0) {
#pragma unroll
        for (int it = 0; it < AG / 256; it++) {
            int c = it * 256 + t;
            gl2lds16(Abase + (size_t)(c >> 2) * K + k0 + (c & 3) * 8, &As[sel][(c - l) * 8]);
        }
#pragma unroll
        for (int it = 0; it < BG / 256; it++) {
            int c = it * 256 + t;
            gl2lds16(Bbase + (size_t)(c >> 2) * K + k0 + (c & 3) * 8, &Bs[sel][(c - l) * 8]);
        }
    };

    stage(0, 0);
    __syncthreads();
    int cur = 0;
    for (int k0 = 0; k0 < K; k0 += 32) {
        if (k0 + 32 < K) stage(cur ^ 1, k0 + 32);
        bf16x8 af[MI], bfr[NI];
#pragma unroll
        for (int i = 0; i < MI; i++)
            af[i] = *(const bf16x8*)&As[cur][(wm + i * 16 + lane16) * 32 + quad * 8];
#pragma unroll
        for (int j = 0; j < NI; j++)
            bfr[j] = *(const bf16x8*)&Bs[cur][(wn + j * 16 + lane16) * 32 + quad * 8];
#pragma unroll
        for (int i = 0; i < MI; i++)
#pragma unroll
            for (int j = 0; j < NI; j++)
                acc[i][j] = __builtin_amdgcn_mfma_f32_16x16x32_bf16(af[i], bfr[j], acc[i][j], 0, 0, 0);
        __syncthreads();
        cur ^= 1;
    }

    // ---- epilogue: two 32-row halves through LDS ----
#pragma unroll
    for (int half = 0; half < 2; half++) {
        if ((w & 1) == half) {
#pragma unroll
            for (int i = 0; i < MI; i++)
#pragma unroll
                for (int j = 0; j < NI; j++)
#pragma unroll
                    for (int r = 0; r < 4; r++)
                        ct[i * 16 + quad * 4 + r][wn + j * 16 + lane16] = acc[i][j][r];
        }
        __syncthreads();
        if (by < 20) {
#pragma unroll
            for (int it = 0; it < 16; it++) {
                int idx = it * 256 + t;
                int row = idx >> 7, d = idx & 127;
                int s = m0 + half * 32 + row;
                float v = ct[row][d];
                float other = ct[row][(d < 64) ? (d + 64) : (d - 64)];
                float c = cosb[s * HD + d], sn = sinb[s * HD + d];
                float rot = (d < 64) ? -other : other;
                float o = v * c + rot * sn;
                if (by < 16)
                    qs[((size_t)by * S + s) * HD + d] = (bf16)(o * 0.04419417382415922f);
                else
                    kb[((size_t)(by - 16) * S + s) * HD + d] = (bf16)o;
            }
        } else {
            int y0 = (by - 20) * 128;
#pragma unroll
            for (int it = 0; it < 16; it++) {
                int idx = it * 256 + t;
                int y = idx >> 5, ss = idx & 31;
                vT[(size_t)(y0 + y) * S + m0 + half * 32 + ss] = (bf16)ct[ss][y];
            }
        }
        __syncthreads();
    }
}

// ---------------- WO GEMM: 64x128 dbuf ----------------
template <int BM, int BN>
__global__ __launch_bounds__(256) void gemm_bt(const bf16* __restrict__ A,
                                               const bf16* __restrict__ B,
                                               float* __restrict__ C, int Ndim, int K) {
    __shared__ bf16 As[2][BM * 32];
    __shared__ bf16 Bs[2][BN * 32];
    int m0 = blockIdx.x * BM, n0 = blockIdx.y * BN;
    int t = threadIdx.x;
    int l = t & 63, w = t >> 6;
    int lane16 = l & 15, quad = l >> 4;

    const bf16* Abase = A + (size_t)m0 * K;
    const bf16* Bbase = B + (size_t)n0 * K;

    constexpr int MI = BM / 32, NI = BN / 32;
    int wm = (w & 1) * (BM / 2), wn = (w >> 1) * (BN / 2);
    f32x4 acc[MI][NI];
#pragma unroll
    for (int i = 0; i < MI; i++)
#pragma unroll
        for (int j = 0; j < NI; j++) acc[i][j] = (f32x4){0.f, 0.f, 0.f, 0.f};

    constexpr int AG = BM * 4;
    constexpr int BG = BN * 4;

    auto stage = [&](int sel, int k0) {
#pragma unroll
        for (int it = 0; it < AG / 256; it++) {
            int c = it * 256 + t;
            gl2lds16(Abase + (size_t)(c >> 2) * K + k0 + (c & 3) * 8, &As[sel][(c - l) * 8]);
        }
#pragma unroll
        for (int it = 0; it < BG / 256; it++) {
            int c = it * 256 + t;
            gl2lds16(Bbase + (size_t)(c >> 2) * K + k0 + (c & 3) * 8, &Bs[sel][(c - l) * 8]);
        }
    };

    stage(0, 0);
    __syncthreads();
    int cur = 0;
    for (int k0 = 0; k0 < K; k0 += 32) {
        if (k0 + 32 < K) stage(cur ^ 1, k0 + 32);
        bf16x8 af[MI], bfr[NI];
#pragma unroll
        for (int i = 0; i < MI; i++)
            af[i] = *(const bf16x8*)&As[cur][(wm + i * 16 + lane16) * 32 + quad * 8];
#pragma unroll
        for (int j = 0; j < NI; j++)
            bfr[j] = *(const bf16x8*)&Bs[cur][(wn + j * 16 + lane16) * 32 + quad * 8];
#pragma unroll
        for (int i = 0; i < MI; i++)
#pragma unroll
            for (int j = 0; j < NI; j++)
                acc[i][j] = __builtin_amdgcn_mfma_f32_16x16x32_bf16(af[i], bfr[j], acc[i][j], 0, 0, 0);
        __syncthreads();
        cur ^= 1;
    }
#pragma unroll
    for (int i = 0; i < MI; i++)
#pragma unroll
        for (int j = 0; j < NI; j++) {
            float* cp = C + (size_t)(m0 + wm + i * 16 + quad * 4) * Ndim + n0 + wn + j * 16 + lane16;
#pragma unroll
            for (int r = 0; r < 4; r++) cp[(size_t)r * Ndim] = acc[i][j][r];
        }
}

// ------- fused attn: full-row f16 score tile in LDS (NO per-lane score registers) -------
// sb[16][SROW] f16 = ~66 KB/block; 2 blocks/CU = 132 KB < 160 KB. Phase A streams MFMA
// scores straight to LDS (barrier-free), Newton sweeps read rows from LDS (not scratch),
// Phase C rewrites scores->P bf16 in place (+fused f32 attn store), PV streams SEGS*8
// MFMA barrier-free. ~4 barriers/body vs ~14. Live set ~30 arch regs -> the
// launch_bounds(1024,8) clamp (32+32) fits with NO spill (xr was the only reason it spilled).
template <int SEGS>
__device__ __forceinline__ void attn_body(const bf16* __restrict__ qs, const bf16* __restrict__ kb,
                                          const bf16* __restrict__ vT, float* __restrict__ attn,
                                          bf16* __restrict__ o, int r0, int h,
                                          _Float16 (&sb)[16][SROW]) {
    int jlen = r0 + 16;  // 16-aligned
    int t = threadIdx.x;
    int l = t & 63;
    int w = t >> 6;  // 0..15
    int lane16 = l & 15, quad = l >> 4;

    const bf16* qrow = qs + ((size_t)h * S + (r0 + lane16)) * HD + quad * 8;
    bf16x8 afrag[4];
#pragma unroll
    for (int kc = 0; kc < 4; kc++) afrag[kc] = *(const bf16x8*)(qrow + kc * 32);

    const bf16* kbase = kb + (size_t)(h >> 2) * S * HD;
    const bf16* vbase = vT + (size_t)(h >> 2) * HD * S;

    // ---- tail memset: cols [jlen, SEGS*512) <- MASKV (disjoint from Phase A writes) ----
    {
        f16x8 mk = {(_Float16)MASKV, (_Float16)MASKV, (_Float16)MASKV, (_Float16)MASKV,
                    (_Float16)MASKV, (_Float16)MASKV, (_Float16)MASKV, (_Float16)MASKV};
        int row = t >> 6;  // 16 rows x 64 threads
        for (int c = jlen + (t & 63) * 8; c < SEGS * 512; c += 512)
            *(f16x8*)&sb[row][c] = mk;
    }

    // ---- Phase A: scores -> f16 LDS, barrier-free MFMA stream ----
#pragma unroll
    for (int sgi = 0; sgi < SEGS; sgi++) {
        int j0 = sgi * 512;
#pragma unroll
        for (int tt = 0; tt < 2; tt++) {
            int jt = j0 + (w + tt * 16) * 16;
            if (jt < jlen) {
                f32x4 acc = {0.f, 0.f, 0.f, 0.f};
                const bf16* kp = kbase + (size_t)(jt + lane16) * HD + quad * 8;
#pragma unroll
                for (int kc = 0; kc < 4; kc++) {
                    bf16x8 b = *(const bf16x8*)(kp + kc * 32);
                    acc = __builtin_amdgcn_mfma_f32_16x16x32_bf16(afrag[kc], b, acc, 0, 0, 0);
                }
                if (jt + 15 > r0) {  // diagonal tile: causal mask
                    int jj = jt + lane16;
#pragma unroll
                    for (int r = 0; r < 4; r++) {
                        float v = acc[r];
                        if (jj > r0 + quad * 4 + r) v = MASKV;
                        sb[quad * 4 + r][jt + lane16] = (_Float16)v;
                    }
                } else {
#pragma unroll
                    for (int r = 0; r < 4; r++)
                        sb[quad * 4 + r][jt + lane16] = (_Float16)acc[r];
                }
            }
        }
    }
    __syncthreads();  // one barrier: all scores resident

    float* arow = attn + ((size_t)h * S + (r0 + w)) * S;

    // ---- zero-fill attn cols [SEGS*512, 2048) (tau-independent; drains under B) ----
    {
        f32x4 z4 = {0.f, 0.f, 0.f, 0.f};
        for (int j = SEGS * 512 + l * 4; j < S; j += 256) nt_store4(z4, &arow[j]);
    }

    // ---- Phase B: entmax-1.5 tau (3 AS + 3 NW), sweeps over LDS row w ----
    const _Float16* myrow = &sb[w][0];
    float mx = MASKV;
#pragma unroll
    for (int j = 0; j < SEGS; j++) {
        f16x8 v = *(const f16x8*)&myrow[j * 512 + l * 8];
#pragma unroll
        for (int e = 0; e < 8; e++) mx = fmaxf(mx, (float)v[e]);
    }
    float m = wave_fmax(mx);
    float taulo = m - 1.0f;
    float tauhi = m - 0.02209709f;  // m - (1/2048)^0.5
    float tau = taulo;

#pragma unroll 1
    for (int it = 0; it < AS_ITERS; it++) {
        float b1 = 0.f, b2 = 0.f, cn = 0.f;
#pragma unroll
        for (int j = 0; j < SEGS; j++) {
            f16x8 v = *(const f16x8*)&myrow[j * 512 + l * 8];
#pragma unroll
            for (int e = 0; e < 8; e++) {
                float d = fmaxf((float)v[e] - tau, 0.f);
                b2 = fmaf(d, d, b2);
                b1 += d;
                cn += (d > 0.f) ? 1.f : 0.f;
            }
        }
        float B1 = wave_sum(b1);
        float B2 = wave_sum(b2);
        float n = wave_sum(cn);
        float disc = fmaxf(B1 * B1 - n * (B2 - 1.0f), 0.f);
        tau += (B1 - __builtin_sqrtf(disc)) / fmaxf(n, 1.0f);
        tau = fminf(fmaxf(tau, taulo), tauhi);
    }
#pragma unroll 1
    for (int it = 0; it < NW_ITERS; it++) {
        float f = 0.f, g = 0.f;
#pragma unroll
        for (int j = 0; j < SEGS; j++) {
            f16x8 v = *(const f16x8*)&myrow[j * 512 + l * 8];
#pragma unroll
            for (int e = 0; e < 8; e++) {
                float d = fmaxf((float)v[e] - tau, 0.f);
                f = fmaf(d, d, f);
                g += d;
            }
        }
        float F = wave_sum(f);
        float G = wave_sum(g);
        tau += (F - 1.0f) / (2.0f * G + 1e-20f);
        tau = fminf(fmaxf(tau, taulo), tauhi);
    }
    float inv;
    {
        float s = 0.f;
#pragma unroll
        for (int j = 0; j < SEGS; j++) {
            f16x8 v = *(const f16x8*)&myrow[j * 512 + l * 8];
#pragma unroll
            for (int e = 0; e < 8; e++) {
                float d = fmaxf((float)v[e] - tau, 0.f);
                s = fmaf(d, d, s);
            }
        }
        inv = 1.0f / wave_sum(s);
    }

    // ---- Phase C: row w scores -> P: f32 nt-store to attn + bf16 in-place to LDS ----
    bf16* prow = (bf16*)&sb[0][0] + (size_t)w * SROW;
#pragma unroll
    for (int j = 0; j < SEGS; j++) {
        int c = j * 512 + l * 8;
        f16x8 v = *(const f16x8*)&myrow[c];
        float p[8];
#pragma unroll
        for (int e = 0; e < 8; e++) {
            float d = fmaxf((float)v[e] - tau, 0.f);
            p[e] = d * d * inv;
        }
        f32x4 p0 = {p[0], p[1], p[2], p[3]};
        f32x4 p1 = {p[4], p[5], p[6], p[7]};
        nt_store4(p0, &arow[c]);
        nt_store4(p1, &arow[c + 4]);
        bf16x8 pb;
#pragma unroll
        for (int e = 0; e < 8; e++) pb[e] = (bf16)p[e];
        *(bf16x8*)&prow[c] = pb;
    }
    __syncthreads();  // P tile fully resident

    // ---- PV: stream SEGS*8 MFMA, barrier-free ----
    const bf16* pbuf = (const bf16*)&sb[0][0];
    int jt_o = (w & 7) * 16;
    int kh = (w >> 3) * 256;
    f32x4 acc_o = {0.f, 0.f, 0.f, 0.f};
#pragma unroll
    for (int sgi = 0; sgi < SEGS; sgi++) {
        int j0 = sgi * 512;
#pragma unroll
        for (int ks = 0; ks < 8; ks++) {
            int kk = kh + ks * 32;
            bf16x8 a = *(const bf16x8*)&pbuf[(size_t)lane16 * SROW + j0 + kk + quad * 8];
            bf16x8 b = *(const bf16x8*)(vbase + (size_t)(jt_o + lane16) * S + j0 + kk + quad * 8);
            acc_o = __builtin_amdgcn_mfma_f32_16x16x32_bf16(a, b, acc_o, 0, 0, 0);
        }
    }

    // ---- Phase D: combine K-halves via f32 scratch view of sb, write O ----
    __syncthreads();  // all PV reads done before sb reuse
    float* fs = (float*)&sb[0][0];
    if (w >= 8) {
#pragma unroll
        for (int r = 0; r < 4; r++) fs[(w - 8) * 256 + l * 4 + r] = acc_o[r];
    }
    __syncthreads();
    if (w < 8) {
        bf16* op = o + (size_t)(r0 + quad * 4) * DM + h * HD + jt_o + lane16;
#pragma unroll
        for (int r = 0; r < 4; r++) {
            float v = acc_o[r] + fs[w * 256 + l * 4 + r];
            op[(size_t)r * DM] = (bf16)v;
        }
    }
}

// 512 persistent blocks (2/CU), classes {4,3,2,1} = 10 segments/block, uniform.
__global__ __launch_bounds__(1024, 8) void attn_av_all(const bf16* __restrict__ qs,
                                                       const bf16* __restrict__ kb,
                                                       const bf16* __restrict__ vT,
                                                       float* __restrict__ attn,
                                                       bf16* __restrict__ o) {
    __shared__ _Float16 sb[16][SROW];  // ~66 KB -> 2 blocks/CU (132 KB < 160 KB)
    int b = blockIdx.x;
    int h = b & 15;
    int qh = b >> 4;
    attn_body<4>(qs, kb, vT, attn, o, (96 + qh) * 16, h, sb);
    __syncthreads();
    attn_body<3>(qs, kb, vT, attn, o, (64 + qh) * 16, h, sb);
    __syncthreads();
    attn_body<2>(qs, kb, vT, attn, o, (32 + qh) * 16, h, sb);
    __syncthreads();
    attn_body<1>(qs, kb, vT, attn, o, qh * 16, h, sb);
}

extern "C" void kernel_launch(void* const* d_in, const int* in_sizes, int n_in,
                              void* d_out, int out_size, void* d_ws, size_t ws_size,
                              hipStream_t stream) {
    const float* hidden = (const float*)d_in[0];
    const float* cosb   = (const float*)d_in[1];
    const float* sinb   = (const float*)d_in[2];
    const float* wq     = (const float*)d_in[3];
    const float* wk     = (const float*)d_in[4];
    const float* wv     = (const float*)d_in[5];
    const float* wo     = (const float*)d_in[6];
    char* ws = (char*)d_ws;
    bf16*  bf_hidden = (bf16*)(ws);                    // 8 MB; reused as O bf16 later
    bf16*  bf_wqkv   = (bf16*)(ws + 8388608);          // 12 MB
    bf16*  bf_wo     = (bf16*)(ws + 20971520);         // 8 MB
    bf16*  qsb       = (bf16*)(ws + 29360128);         // 8 MB  [H][S][HD]
    bf16*  kbb       = (bf16*)(ws + 37748736);         // 2 MB  [4][S][HD]
    bf16*  vTb       = (bf16*)(ws + 39845888);         // 2 MB  [4][HD][S]
    float* out  = (float*)d_out;
    float* attn = out + 4194304;

    cvt_all<<<dim3(14336), 256, 0, stream>>>(hidden, wq, wk, wv, wo, bf_hidden, bf_wqkv, bf_wo);

    // QKV projection with fused RoPE + V-transpose epilogue (768 blocks = 3/CU balanced)
    gemm_qkv_rope<<<dim3(32, 24), 256, 0, stream>>>(bf_hidden, bf_wqkv, cosb, sinb,
                                                    qsb, kbb, vTb);

    // fused scores + entmax + P.V + attn write  (512 persistent blocks, 2/CU)
    attn_av_all<<<dim3(512), 1024, 0, stream>>>(qsb, kbb, vTb, attn, bf_hidden);

    // out = O @ wo^T  (512 blocks = 2/CU balanced)
    gemm_bt<64, 128><<<dim3(32, 16), 256, 0, stream>>>(bf_hidden, bf_wo, out, DM, DM);
}

// Round 11
// 564.403 us; speedup vs baseline: 1.1039x; 1.0001x over previous
//
#include <hip/hip_runtime.h>

typedef __bf16 bf16;
typedef __bf16 bf16x4 __attribute__((ext_vector_type(4)));
typedef __bf16 bf16x8 __attribute__((ext_vector_type(8)));
typedef float f32x4 __attribute__((ext_vector_type(4)));
typedef float f32x2 __attribute__((ext_vector_type(2)));

#define S 2048
#define DM 2048
#define HD 128
#define H 16
#define NQKV 3072
#define AS_ITERS 3
#define NW_ITERS 3
#define BROW 556  // f32 row stride of attn LDS buf; 556%32=12 -> no bank conflicts (R3-R9)

__device__ __forceinline__ void gl2lds16(const void* g, void* l) {
    __builtin_amdgcn_global_load_lds(
        (const __attribute__((address_space(1))) void*)g,
        (__attribute__((address_space(3))) void*)l, 16, 0, 0);
}

__device__ __forceinline__ void nt_store4(f32x4 v, float* p) {
    __builtin_nontemporal_store(v, (f32x4*)p);
}

// ---------------- DPP-based wave(64) reductions ----------------
template <int CTRL, int RM>
__device__ __forceinline__ float dpp_zero(float x) {
    return __builtin_bit_cast(float, __builtin_amdgcn_update_dpp(
        0, __builtin_bit_cast(int, x), CTRL, RM, 0xf, false));
}
template <int CTRL, int RM>
__device__ __forceinline__ float dpp_self(float x) {
    int xi = __builtin_bit_cast(int, x);
    return __builtin_bit_cast(float, __builtin_amdgcn_update_dpp(xi, xi, CTRL, RM, 0xf, false));
}
__device__ __forceinline__ float wave_bcast63(float x) {
    return __builtin_bit_cast(float, __builtin_amdgcn_readlane(__builtin_bit_cast(int, x), 63));
}
__device__ __forceinline__ float wave_sum(float x) {
    x += dpp_zero<0x111, 0xf>(x);
    x += dpp_zero<0x112, 0xf>(x);
    x += dpp_zero<0x114, 0xf>(x);
    x += dpp_zero<0x118, 0xf>(x);
    x += dpp_zero<0x142, 0xa>(x);
    x += dpp_zero<0x143, 0xc>(x);
    return wave_bcast63(x);
}
__device__ __forceinline__ float wave_fmax(float x) {
    x = fmaxf(x, dpp_self<0x111, 0xf>(x));
    x = fmaxf(x, dpp_self<0x112, 0xf>(x));
    x = fmaxf(x, dpp_self<0x114, 0xf>(x));
    x = fmaxf(x, dpp_self<0x118, 0xf>(x));
    x = fmaxf(x, dpp_self<0x142, 0xa>(x));
    x = fmaxf(x, dpp_self<0x143, 0xc>(x));
    return wave_bcast63(x);
}

// ---------------- fused fp32 -> bf16 convert for all 5 inputs (float4 granules) ----------------
__global__ void cvt_all(const float* __restrict__ hid, const float* __restrict__ wq,
                        const float* __restrict__ wk, const float* __restrict__ wv,
                        const float* __restrict__ wo, bf16* __restrict__ bh,
                        bf16* __restrict__ bqkv, bf16* __restrict__ bwo) {
    int i = blockIdx.x * blockDim.x + threadIdx.x;
    const float* src;
    bf16* dst;
    int off;
    if (i < 1048576) { src = hid; dst = bh; off = i; }
    else if (i < 2097152) { src = wq; dst = bqkv; off = i - 1048576; }
    else if (i < 2359296) { src = wk; dst = bqkv + 2048 * 2048; off = i - 2097152; }
    else if (i < 2621440) { src = wv; dst = bqkv + 2048 * 2048 + 512 * 2048; off = i - 2359296; }
    else { src = wo; dst = bwo; off = i - 2621440; }
    float4 f = ((const float4*)src)[off];
    bf16x4 o;
    o[0] = (bf16)f.x; o[1] = (bf16)f.y; o[2] = (bf16)f.z; o[3] = (bf16)f.w;
    ((bf16x4*)dst)[off] = o;
}

// ---------------- QKV GEMM: 128x128 tile (R8-proven), dbuf, FUSED RoPE + V-transpose ----
// grid (16, 24). by<16 -> Q head by; 16<=by<20 -> K kv=by-16; by>=20 -> V y0=(by-20)*128.
// Epilogue: 4 x 32-row halves staged through ct[32][129] ALIASED onto the staging LDS
// (smem is free after the K-loop) -> no extra LDS vs plain gemm128.
__global__ __launch_bounds__(256) void gemm_qkv_rope(const bf16* __restrict__ A,
                                                     const bf16* __restrict__ B,
                                                     const float* __restrict__ cosb,
                                                     const float* __restrict__ sinb,
                                                     bf16* __restrict__ qs,
                                                     bf16* __restrict__ kb,
                                                     bf16* __restrict__ vT) {
    constexpr int K = DM;
    __shared__ bf16 smem[2][8192];  // [sel][ As: 0..4095 | Bs: 4096..8191 ]  (32 KB)
    int m0 = blockIdx.x * 128;
    int by = blockIdx.y;
    int n0 = by * 128;
    int t = threadIdx.x;
    int l = t & 63, w = t >> 6;
    int lane16 = l & 15, quad = l >> 4;

    int c0 = (w * 2) * 64 + l;
    int c1 = c0 + 64;
    const bf16* Abase = A + (size_t)m0 * K;
    const bf16* Bbase = B + (size_t)n0 * K;

    int wm = (w & 1) * 64, wn = (w >> 1) * 64;
    f32x4 acc[4][4];
#pragma unroll
    for (int i = 0; i < 4; i++)
#pragma unroll
        for (int j = 0; j < 4; j++) acc[i][j] = (f32x4){0.f, 0.f, 0.f, 0.f};

    auto stage = [&](int sel, int k0) {
        bf16* As = &smem[sel][0];
        bf16* Bs = &smem[sel][4096];
        gl2lds16(Abase + (size_t)(c0 >> 2) * K + k0 + (c0 & 3) * 8, &As[(w * 2) * 512]);
        gl2lds16(Abase + (size_t)(c1 >> 2) * K + k0 + (c1 & 3) * 8, &As[(w * 2 + 1) * 512]);
        gl2lds16(Bbase + (size_t)(c0 >> 2) * K + k0 + (c0 & 3) * 8, &Bs[(w * 2) * 512]);
        gl2lds16(Bbase + (size_t)(c1 >> 2) * K + k0 + (c1 & 3) * 8, &Bs[(w * 2 + 1) * 512]);
    };

    stage(0, 0);
    __syncthreads();
    int cur = 0;
    for (int k0 = 0; k0 < K; k0 += 32) {
        if (k0 + 32 < K) stage(cur ^ 1, k0 + 32);  // prefetch overlaps ds_read+MFMA
        const bf16* As = &smem[cur][0];
        const bf16* Bs = &smem[cur][4096];
        bf16x8 af[4], bfr[4];
#pragma unroll
        for (int i = 0; i < 4; i++)
            af[i] = *(const bf16x8*)&As[(wm + i * 16 + lane16) * 32 + quad * 8];
#pragma unroll
        for (int j = 0; j < 4; j++)
            bfr[j] = *(const bf16x8*)&Bs[(wn + j * 16 + lane16) * 32 + quad * 8];
#pragma unroll
        for (int i = 0; i < 4; i++)
#pragma unroll
            for (int j = 0; j < 4; j++)
                acc[i][j] = __builtin_amdgcn_mfma_f32_16x16x32_bf16(af[i], bfr[j], acc[i][j], 0, 0, 0);
        __syncthreads();
        cur ^= 1;
    }

    // ---- fused epilogue: 4 halves of 32 rows through ct (aliases staging LDS) ----
    float (*ct)[129] = (float(*)[129]) & smem[0][0];  // 16.5 KB < 32 KB available
#pragma unroll
    for (int hf = 0; hf < 4; hf++) {
        if ((w & 1) == (hf >> 1)) {  // waves owning rows [hf*32, hf*32+32)
            int ibase = (hf & 1) * 2;
#pragma unroll
            for (int ii = 0; ii < 2; ii++)
#pragma unroll
                for (int j = 0; j < 4; j++)
#pragma unroll
                    for (int r = 0; r < 4; r++)
                        ct[ii * 16 + quad * 4 + r][wn + j * 16 + lane16] = acc[ibase + ii][j][r];
        }
        __syncthreads();
        if (by < 20) {
            // q (by<16) or k: RoPE; 32x128 elems, 16/thread, lanes -> consecutive d.
#pragma unroll
            for (int it2 = 0; it2 < 16; it2++) {
                int idx = it2 * 256 + t;
                int row = idx >> 7, d = idx & 127;
                int s = m0 + hf * 32 + row;
                float v = ct[row][d];
                float other = ct[row][(d < 64) ? (d + 64) : (d - 64)];
                float c = cosb[s * HD + d], sn = sinb[s * HD + d];
                float rot = (d < 64) ? -other : other;
                float o = v * c + rot * sn;
                if (by < 16)
                    qs[((size_t)by * S + s) * HD + d] = (bf16)(o * 0.04419417382415922f);
                else
                    kb[((size_t)(by - 16) * S + s) * HD + d] = (bf16)o;
            }
        } else {
            // V: transposed write, coalesced in s; ct column reads conflict-free (pad 129).
            int y0 = (by - 20) * 128;
#pragma unroll
            for (int it2 = 0; it2 < 16; it2++) {
                int idx = it2 * 256 + t;
                int y = idx >> 5, ss = idx & 31;
                vT[(size_t)(y0 + y) * S + m0 + hf * 32 + ss] = (bf16)ct[ss][y];
            }
        }
        __syncthreads();
    }
}

// ---------------- WO GEMM: 128x128 tile, dbuf (R8-proven) ----------------
__global__ __launch_bounds__(256) void gemm128_bt(const bf16* __restrict__ A,
                                                  const bf16* __restrict__ B,
                                                  float* __restrict__ C, int Ndim, int K) {
    __shared__ bf16 As[2][128 * 32];
    __shared__ bf16 Bs[2][128 * 32];
    int m0 = blockIdx.x * 128, n0 = blockIdx.y * 128;
    int t = threadIdx.x;
    int l = t & 63, w = t >> 6;
    int lane16 = l & 15, quad = l >> 4;

    int c0 = (w * 2) * 64 + l;
    int c1 = c0 + 64;
    const bf16* Abase = A + (size_t)m0 * K;
    const bf16* Bbase = B + (size_t)n0 * K;

    int wm = (w & 1) * 64, wn = (w >> 1) * 64;
    f32x4 acc[4][4];
#pragma unroll
    for (int i = 0; i < 4; i++)
#pragma unroll
        for (int j = 0; j < 4; j++) acc[i][j] = (f32x4){0.f, 0.f, 0.f, 0.f};

    auto stage = [&](int sel, int k0) {
        gl2lds16(Abase + (size_t)(c0 >> 2) * K + k0 + (c0 & 3) * 8, &As[sel][(w * 2) * 512]);
        gl2lds16(Abase + (size_t)(c1 >> 2) * K + k0 + (c1 & 3) * 8, &As[sel][(w * 2 + 1) * 512]);
        gl2lds16(Bbase + (size_t)(c0 >> 2) * K + k0 + (c0 & 3) * 8, &Bs[sel][(w * 2) * 512]);
        gl2lds16(Bbase + (size_t)(c1 >> 2) * K + k0 + (c1 & 3) * 8, &Bs[sel][(w * 2 + 1) * 512]);
    };

    stage(0, 0);
    __syncthreads();
    int cur = 0;
    for (int k0 = 0; k0 < K; k0 += 32) {
        if (k0 + 32 < K) stage(cur ^ 1, k0 + 32);
        bf16x8 af[4], bfr[4];
#pragma unroll
        for (int i = 0; i < 4; i++)
            af[i] = *(const bf16x8*)&As[cur][(wm + i * 16 + lane16) * 32 + quad * 8];
#pragma unroll
        for (int j = 0; j < 4; j++)
            bfr[j] = *(const bf16x8*)&Bs[cur][(wn + j * 16 + lane16) * 32 + quad * 8];
#pragma unroll
        for (int i = 0; i < 4; i++)
#pragma unroll
            for (int j = 0; j < 4; j++)
                acc[i][j] = __builtin_amdgcn_mfma_f32_16x16x32_bf16(af[i], bfr[j], acc[i][j], 0, 0, 0);
        __syncthreads();
        cur ^= 1;
    }
#pragma unroll
    for (int i = 0; i < 4; i++)
#pragma unroll
        for (int j = 0; j < 4; j++) {
            float* cp = C + (size_t)(m0 + wm + i * 16 + quad * 4) * Ndim + n0 + wn + j * 16 + lane16;
#pragma unroll
            for (int r = 0; r < 4; r++) cp[(size_t)r * Ndim] = acc[i][j][r];
        }
}

// ------- fused attn (R9 verbatim; best measured 213 us profiled) -------
template <int SEGS>
__device__ __forceinline__ void attn_body(const bf16* __restrict__ qs, const bf16* __restrict__ kb,
                                          const bf16* __restrict__ vT, float* __restrict__ attn,
                                          bf16* __restrict__ o, int r0, int h,
                                          float (&buf)[16][BROW]) {
    constexpr int NREG2 = SEGS * 4;  // f32x2 regs per lane (= SEGS*8 scores)
    int jlen = r0 + 16;
    int l = threadIdx.x & 63;
    int w = threadIdx.x >> 6;  // 0..15
    int lane16 = l & 15, quad = l >> 4;

    const bf16* qrow = qs + ((size_t)h * S + (r0 + lane16)) * HD + quad * 8;
    bf16x8 afrag[4];
#pragma unroll
    for (int kc = 0; kc < 4; kc++) afrag[kc] = *(const bf16x8*)(qrow + kc * 32);

    const bf16* kbase = kb + (size_t)(h >> 2) * S * HD;
    const bf16* vbase = vT + (size_t)(h >> 2) * HD * S;
    f32x2 xr[NREG2];

    // ---- Phase A: scores into registers; single f32 buffer, 2 barriers/segment ----
#pragma unroll
    for (int sgi = 0; sgi < SEGS; sgi++) {
        int j0 = sgi * 512;
#pragma unroll
        for (int tt = 0; tt < 2; tt++) {
            int t = w + tt * 16;
            int jt = j0 + t * 16;
            if (jt < jlen) {
                f32x4 acc = {0.f, 0.f, 0.f, 0.f};
                const bf16* kp = kbase + (size_t)(jt + lane16) * HD + quad * 8;
#pragma unroll
                for (int kc = 0; kc < 4; kc++) {
                    bf16x8 b = *(const bf16x8*)(kp + kc * 32);
                    acc = __builtin_amdgcn_mfma_f32_16x16x32_bf16(afrag[kc], b, acc, 0, 0, 0);
                }
                if (jt + 15 > r0) {  // diagonal tile: apply causal mask
                    int jj = jt + lane16;
#pragma unroll
                    for (int r = 0; r < 4; r++) {
                        int rowi = quad * 4 + r;
                        float v = acc[r];
                        if (jj > r0 + rowi) v = -1e30f;
                        buf[rowi][t * 16 + lane16] = v;
                    }
                } else {
#pragma unroll
                    for (int r = 0; r < 4; r++) buf[quad * 4 + r][t * 16 + lane16] = acc[r];
                }
            }
        }
        __syncthreads();
#pragma unroll
        for (int part = 0; part < 2; part++) {
            float4 fq = *(const float4*)&buf[w][part * 256 + l * 4];
            if (sgi == SEGS - 1) {
                int jb = j0 + part * 256 + l * 4;
                xr[sgi * 4 + part * 2 + 0] =
                    (f32x2){(jb + 0 < jlen) ? fq.x : -1e30f, (jb + 1 < jlen) ? fq.y : -1e30f};
                xr[sgi * 4 + part * 2 + 1] =
                    (f32x2){(jb + 2 < jlen) ? fq.z : -1e30f, (jb + 3 < jlen) ? fq.w : -1e30f};
            } else {
                xr[sgi * 4 + part * 2 + 0] = (f32x2){fq.x, fq.y};
                xr[sgi * 4 + part * 2 + 1] = (f32x2){fq.z, fq.w};
            }
        }
        __syncthreads();
    }

    float* arow = attn + ((size_t)h * S + (r0 + w)) * S;

    // ---- Phase E (early; tau-independent): zero-fill strictly-upper region ----
    {
        f32x4 z4 = {0.f, 0.f, 0.f, 0.f};
        for (int j = SEGS * 512 + l * 4; j < S; j += 256) nt_store4(z4, &arow[j]);
    }

    // ---- Phase B: entmax-1.5 tau: 3 active-set steps + 3 Newton polish ----
    const f32x2 z2 = {0.f, 0.f};
    float mx = -1e30f;
#pragma unroll
    for (int c = 0; c < NREG2; c++) mx = fmaxf(mx, fmaxf(xr[c][0], xr[c][1]));
    float m = wave_fmax(mx);
    float taulo = m - 1.0f;
    float tauhi = m - 0.02209709f;  // m - (1/2048)^0.5
    float tau = taulo;

#pragma unroll 1
    for (int it = 0; it < AS_ITERS; it++) {
        f32x2 tvi = {tau, tau};
        f32x2 b1a = z2, b1b = z2, b2a = z2, b2b = z2, cna = z2, cnb = z2;
#pragma unroll
        for (int c = 0; c < NREG2; c += 2) {
            f32x2 t0 = __builtin_elementwise_max(xr[c] - tvi, z2);
            b2a += t0 * t0; b1a += t0;
            cna += (f32x2){t0[0] > 0.f ? 1.f : 0.f, t0[1] > 0.f ? 1.f : 0.f};
            f32x2 t1 = __builtin_elementwise_max(xr[c + 1] - tvi, z2);
            b2b += t1 * t1; b1b += t1;
            cnb += (f32x2){t1[0] > 0.f ? 1.f : 0.f, t1[1] > 0.f ? 1.f : 0.f};
        }
        f32x2 s1 = b1a + b1b, s2 = b2a + b2b, sc = cna + cnb;
        float B1 = wave_sum(s1[0] + s1[1]);
        float B2 = wave_sum(s2[0] + s2[1]);
        float n = wave_sum(sc[0] + sc[1]);
        float disc = fmaxf(B1 * B1 - n * (B2 - 1.0f), 0.f);
        tau += (B1 - __builtin_sqrtf(disc)) / fmaxf(n, 1.0f);
        tau = fminf(fmaxf(tau, taulo), tauhi);
    }
#pragma unroll 1
    for (int it = 0; it < NW_ITERS; it++) {
        f32x2 tvi = {tau, tau};
        f32x2 fa = z2, fb = z2, ga = z2, gb = z2;
#pragma unroll
        for (int c = 0; c < NREG2; c += 2) {
            f32x2 t0 = __builtin_elementwise_max(xr[c] - tvi, z2);
            fa += t0 * t0; ga += t0;
            f32x2 t1 = __builtin_elementwise_max(xr[c + 1] - tvi, z2);
            fb += t1 * t1; gb += t1;
        }
        f32x2 fv = fa + fb, gv = ga + gb;
        float f = wave_sum(fv[0] + fv[1]);
        float g = wave_sum(gv[0] + gv[1]);
        tau += (f - 1.0f) / (2.0f * g + 1e-20f);
        tau = fminf(fmaxf(tau, taulo), tauhi);
    }

    f32x2 tv = {tau, tau};
    float inv;
    {
        f32x2 sa = z2, sbv = z2;
#pragma unroll
        for (int c = 0; c < NREG2; c += 2) {
            f32x2 t0 = __builtin_elementwise_max(xr[c] - tv, z2);
            sa += t0 * t0;
            f32x2 t1 = __builtin_elementwise_max(xr[c + 1] - tv, z2);
            sbv += t1 * t1;
        }
        f32x2 sv = sa + sbv;
        float ssum = wave_sum(sv[0] + sv[1]);
        inv = 1.0f / ssum;
    }

    // ---- Phase C: P f32 -> attn global (fused; xr dies here) + P bf16 -> LDS
    //      (ping-pong halves), P.V MFMA; 1 barrier/segment ----
    int jt_o = (w & 7) * 16;
    int kh = (w >> 3) * 256;
    f32x4 acc_o = {0.f, 0.f, 0.f, 0.f};
    f32x2 inv2 = {inv, inv};

#pragma unroll
    for (int sgi = 0; sgi < SEGS; sgi++) {
        int j0 = sgi * 512;
        bf16 (*pb)[BROW] = (bf16(*)[BROW])(&buf[0][0]) + (sgi & 1) * 16;
#pragma unroll
        for (int part = 0; part < 2; part++) {
            f32x2 ta = __builtin_elementwise_max(xr[sgi * 4 + part * 2 + 0] - tv, z2);
            f32x2 tb = __builtin_elementwise_max(xr[sgi * 4 + part * 2 + 1] - tv, z2);
            f32x2 pa = (ta * ta) * inv2;
            f32x2 pb2 = (tb * tb) * inv2;
            f32x4 pv = {pa[0], pa[1], pb2[0], pb2[1]};
            nt_store4(pv, &arow[j0 + part * 256 + l * 4]);
            bf16x4 pbv;
            pbv[0] = (bf16)pv[0]; pbv[1] = (bf16)pv[1];
            pbv[2] = (bf16)pv[2]; pbv[3] = (bf16)pv[3];
            *(bf16x4*)&pb[w][part * 256 + l * 4] = pbv;
        }
        __syncthreads();
#pragma unroll
        for (int ks = 0; ks < 8; ks++) {
            int kk = kh + ks * 32;
            bf16x8 a = *(const bf16x8*)&pb[lane16][kk + quad * 8];
            bf16x8 b = *(const bf16x8*)(vbase + (size_t)(jt_o + lane16) * S + j0 + kk + quad * 8);
            acc_o = __builtin_amdgcn_mfma_f32_16x16x32_bf16(a, b, acc_o, 0, 0, 0);
        }
    }

    // ---- Phase D: combine K-halves, write O ----
    __syncthreads();
    if (w >= 8) {
#pragma unroll
        for (int r = 0; r < 4; r++) buf[w - 8][l * 4 + r] = acc_o[r];
    }
    __syncthreads();
    if (w < 8) {
        bf16* op = o + (size_t)(r0 + quad * 4) * DM + h * HD + jt_o + lane16;
#pragma unroll
        for (int r = 0; r < 4; r++) {
            float v = acc_o[r] + buf[w][l * 4 + r];
            op[(size_t)r * DM] = (bf16)v;
        }
    }
}

// 512 persistent blocks (2/CU), classes {4,3,2,1} = 10 segments/block, uniform.
__global__ __launch_bounds__(1024, 8) void attn_av_all(const bf16* __restrict__ qs,
                                                       const bf16* __restrict__ kb,
                                                       const bf16* __restrict__ vT,
                                                       float* __restrict__ attn,
                                                       bf16* __restrict__ o) {
    __shared__ float buf[16][BROW];
    int b = blockIdx.x;
    int h = b & 15;
    int qh = b >> 4;
    attn_body<4>(qs, kb, vT, attn, o, (96 + qh) * 16, h, buf);
    __syncthreads();
    attn_body<3>(qs, kb, vT, attn, o, (64 + qh) * 16, h, buf);
    __syncthreads();
    attn_body<2>(qs, kb, vT, attn, o, (32 + qh) * 16, h, buf);
    __syncthreads();
    attn_body<1>(qs, kb, vT, attn, o, qh * 16, h, buf);
}

extern "C" void kernel_launch(void* const* d_in, const int* in_sizes, int n_in,
                              void* d_out, int out_size, void* d_ws, size_t ws_size,
                              hipStream_t stream) {
    const float* hidden = (const float*)d_in[0];
    const float* cosb   = (const float*)d_in[1];
    const float* sinb   = (const float*)d_in[2];
    const float* wq     = (const float*)d_in[3];
    const float* wk     = (const float*)d_in[4];
    const float* wv     = (const float*)d_in[5];
    const float* wo     = (const float*)d_in[6];
    char* ws = (char*)d_ws;
    bf16*  bf_hidden = (bf16*)(ws);                    // 8 MB; reused as O bf16 later
    bf16*  bf_wqkv   = (bf16*)(ws + 8388608);          // 12 MB
    bf16*  bf_wo     = (bf16*)(ws + 20971520);         // 8 MB
    bf16*  qsb       = (bf16*)(ws + 29360128);         // 8 MB  [H][S][HD]
    bf16*  kbb       = (bf16*)(ws + 37748736);         // 2 MB  [4][S][HD]
    bf16*  vTb       = (bf16*)(ws + 39845888);         // 2 MB  [4][HD][S]
    float* out  = (float*)d_out;
    float* attn = out + 4194304;

    cvt_all<<<dim3(14336), 256, 0, stream>>>(hidden, wq, wk, wv, wo, bf_hidden, bf_wqkv, bf_wo);

    // QKV projection, 128x128 tile, fused RoPE + V-transpose epilogue (grid 16x24)
    gemm_qkv_rope<<<dim3(16, 24), 256, 0, stream>>>(bf_hidden, bf_wqkv, cosb, sinb,
                                                    qsb, kbb, vTb);

    // fused scores + entmax + P.V + attn write  (512 persistent blocks, 2/CU)
    attn_av_all<<<dim3(512), 1024, 0, stream>>>(qsb, kbb, vTb, attn, bf_hidden);

    // out = O @ wo^T, 128x128 tile (grid 16x16)
    gemm128_bt<<<dim3(16, 16), 256, 0, stream>>>(bf_hidden, bf_wo, out, DM, DM);
}

// Round 12
// 563.677 us; speedup vs baseline: 1.1053x; 1.0013x over previous
//
#include <hip/hip_runtime.h>

typedef __bf16 bf16;
typedef __bf16 bf16x4 __attribute__((ext_vector_type(4)));
typedef __bf16 bf16x8 __attribute__((ext_vector_type(8)));
typedef float f32x4 __attribute__((ext_vector_type(4)));
typedef float f32x2 __attribute__((ext_vector_type(2)));

#define S 2048
#define DM 2048
#define HD 128
#define H 16
#define NQKV 3072
#define AS_ITERS 2
#define NW_ITERS 2
#define BROW 556  // f32 row stride of attn LDS buf; 556%32=12 -> no bank conflicts (R3-R11)

__device__ __forceinline__ void gl2lds16(const void* g, void* l) {
    __builtin_amdgcn_global_load_lds(
        (const __attribute__((address_space(1))) void*)g,
        (__attribute__((address_space(3))) void*)l, 16, 0, 0);
}

__device__ __forceinline__ void nt_store4(f32x4 v, float* p) {
    __builtin_nontemporal_store(v, (f32x4*)p);
}

// ---------------- DPP-based wave(64) reductions ----------------
template <int CTRL, int RM>
__device__ __forceinline__ float dpp_zero(float x) {
    return __builtin_bit_cast(float, __builtin_amdgcn_update_dpp(
        0, __builtin_bit_cast(int, x), CTRL, RM, 0xf, false));
}
template <int CTRL, int RM>
__device__ __forceinline__ float dpp_self(float x) {
    int xi = __builtin_bit_cast(int, x);
    return __builtin_bit_cast(float, __builtin_amdgcn_update_dpp(xi, xi, CTRL, RM, 0xf, false));
}
__device__ __forceinline__ float wave_bcast63(float x) {
    return __builtin_bit_cast(float, __builtin_amdgcn_readlane(__builtin_bit_cast(int, x), 63));
}
__device__ __forceinline__ float wave_sum(float x) {
    x += dpp_zero<0x111, 0xf>(x);
    x += dpp_zero<0x112, 0xf>(x);
    x += dpp_zero<0x114, 0xf>(x);
    x += dpp_zero<0x118, 0xf>(x);
    x += dpp_zero<0x142, 0xa>(x);
    x += dpp_zero<0x143, 0xc>(x);
    return wave_bcast63(x);
}
__device__ __forceinline__ float wave_fmax(float x) {
    x = fmaxf(x, dpp_self<0x111, 0xf>(x));
    x = fmaxf(x, dpp_self<0x112, 0xf>(x));
    x = fmaxf(x, dpp_self<0x114, 0xf>(x));
    x = fmaxf(x, dpp_self<0x118, 0xf>(x));
    x = fmaxf(x, dpp_self<0x142, 0xa>(x));
    x = fmaxf(x, dpp_self<0x143, 0xc>(x));
    return wave_bcast63(x);
}

// ---------------- fused fp32 -> bf16 convert for all 5 inputs (float4 granules) ----------------
__global__ void cvt_all(const float* __restrict__ hid, const float* __restrict__ wq,
                        const float* __restrict__ wk, const float* __restrict__ wv,
                        const float* __restrict__ wo, bf16* __restrict__ bh,
                        bf16* __restrict__ bqkv, bf16* __restrict__ bwo) {
    int i = blockIdx.x * blockDim.x + threadIdx.x;
    const float* src;
    bf16* dst;
    int off;
    if (i < 1048576) { src = hid; dst = bh; off = i; }
    else if (i < 2097152) { src = wq; dst = bqkv; off = i - 1048576; }
    else if (i < 2359296) { src = wk; dst = bqkv + 2048 * 2048; off = i - 2097152; }
    else if (i < 2621440) { src = wv; dst = bqkv + 2048 * 2048 + 512 * 2048; off = i - 2359296; }
    else { src = wo; dst = bwo; off = i - 2621440; }
    float4 f = ((const float4*)src)[off];
    bf16x4 o;
    o[0] = (bf16)f.x; o[1] = (bf16)f.y; o[2] = (bf16)f.z; o[3] = (bf16)f.w;
    ((bf16x4*)dst)[off] = o;
}

// ---------------- QKV GEMM (64x128, dbuf) with FUSED RoPE + V-transpose epilogue --------
// R9-proven (best measured rest). grid (32,24) = 768 blocks = 3/CU balanced.
__global__ __launch_bounds__(256) void gemm_qkv_rope(const bf16* __restrict__ A,
                                                     const bf16* __restrict__ B,
                                                     const float* __restrict__ cosb,
                                                     const float* __restrict__ sinb,
                                                     bf16* __restrict__ qs,
                                                     bf16* __restrict__ kb,
                                                     bf16* __restrict__ vT) {
    constexpr int BM = 64, BN = 128, K = DM;
    __shared__ bf16 As[2][BM * 32];
    __shared__ bf16 Bs[2][BN * 32];
    __shared__ float ct[32][129];
    int m0 = blockIdx.x * BM;
    int by = blockIdx.y;
    int n0 = by * BN;
    int t = threadIdx.x;
    int l = t & 63, w = t >> 6;
    int lane16 = l & 15, quad = l >> 4;

    const bf16* Abase = A + (size_t)m0 * K;
    const bf16* Bbase = B + (size_t)n0 * K;

    constexpr int MI = BM / 32, NI = BN / 32;
    int wm = (w & 1) * (BM / 2), wn = (w >> 1) * (BN / 2);
    f32x4 acc[MI][NI];
#pragma unroll
    for (int i = 0; i < MI; i++)
#pragma unroll
        for (int j = 0; j < NI; j++) acc[i][j] = (f32x4){0.f, 0.f, 0.f, 0.f};

    constexpr int AG = BM * 4;
    constexpr int BG = BN * 4;

    auto stage = [&](int sel, int k0) {
#pragma unroll
        for (int it = 0; it < AG / 256; it++) {
            int c = it * 256 + t;
            gl2lds16(Abase + (size_t)(c >> 2) * K + k0 + (c & 3) * 8, &As[sel][(c - l) * 8]);
        }
#pragma unroll
        for (int it = 0; it < BG / 256; it++) {
            int c = it * 256 + t;
            gl2lds16(Bbase + (size_t)(c >> 2) * K + k0 + (c & 3) * 8, &Bs[sel][(c - l) * 8]);
        }
    };

    stage(0, 0);
    __syncthreads();
    int cur = 0;
    for (int k0 = 0; k0 < K; k0 += 32) {
        if (k0 + 32 < K) stage(cur ^ 1, k0 + 32);
        bf16x8 af[MI], bfr[NI];
#pragma unroll
        for (int i = 0; i < MI; i++)
            af[i] = *(const bf16x8*)&As[cur][(wm + i * 16 + lane16) * 32 + quad * 8];
#pragma unroll
        for (int j = 0; j < NI; j++)
            bfr[j] = *(const bf16x8*)&Bs[cur][(wn + j * 16 + lane16) * 32 + quad * 8];
#pragma unroll
        for (int i = 0; i < MI; i++)
#pragma unroll
            for (int j = 0; j < NI; j++)
                acc[i][j] = __builtin_amdgcn_mfma_f32_16x16x32_bf16(af[i], bfr[j], acc[i][j], 0, 0, 0);
        __syncthreads();
        cur ^= 1;
    }

    // ---- epilogue: two 32-row halves through LDS ----
#pragma unroll
    for (int half = 0; half < 2; half++) {
        if ((w & 1) == half) {
#pragma unroll
            for (int i = 0; i < MI; i++)
#pragma unroll
                for (int j = 0; j < NI; j++)
#pragma unroll
                    for (int r = 0; r < 4; r++)
                        ct[i * 16 + quad * 4 + r][wn + j * 16 + lane16] = acc[i][j][r];
        }
        __syncthreads();
        if (by < 20) {
#pragma unroll
            for (int it = 0; it < 16; it++) {
                int idx = it * 256 + t;
                int row = idx >> 7, d = idx & 127;
                int s = m0 + half * 32 + row;
                float v = ct[row][d];
                float other = ct[row][(d < 64) ? (d + 64) : (d - 64)];
                float c = cosb[s * HD + d], sn = sinb[s * HD + d];
                float rot = (d < 64) ? -other : other;
                float o = v * c + rot * sn;
                if (by < 16)
                    qs[((size_t)by * S + s) * HD + d] = (bf16)(o * 0.04419417382415922f);
                else
                    kb[((size_t)(by - 16) * S + s) * HD + d] = (bf16)o;
            }
        } else {
            int y0 = (by - 20) * 128;
#pragma unroll
            for (int it = 0; it < 16; it++) {
                int idx = it * 256 + t;
                int y = idx >> 5, ss = idx & 31;
                vT[(size_t)(y0 + y) * S + m0 + half * 32 + ss] = (bf16)ct[ss][y];
            }
        }
        __syncthreads();
    }
}

// ---------------- WO GEMM: 64x128 dbuf (R9-proven) ----------------
template <int BM, int BN>
__global__ __launch_bounds__(256) void gemm_bt(const bf16* __restrict__ A,
                                               const bf16* __restrict__ B,
                                               float* __restrict__ C, int Ndim, int K) {
    __shared__ bf16 As[2][BM * 32];
    __shared__ bf16 Bs[2][BN * 32];
    int m0 = blockIdx.x * BM, n0 = blockIdx.y * BN;
    int t = threadIdx.x;
    int l = t & 63, w = t >> 6;
    int lane16 = l & 15, quad = l >> 4;

    const bf16* Abase = A + (size_t)m0 * K;
    const bf16* Bbase = B + (size_t)n0 * K;

    constexpr int MI = BM / 32, NI = BN / 32;
    int wm = (w & 1) * (BM / 2), wn = (w >> 1) * (BN / 2);
    f32x4 acc[MI][NI];
#pragma unroll
    for (int i = 0; i < MI; i++)
#pragma unroll
        for (int j = 0; j < NI; j++) acc[i][j] = (f32x4){0.f, 0.f, 0.f, 0.f};

    constexpr int AG = BM * 4;
    constexpr int BG = BN * 4;

    auto stage = [&](int sel, int k0) {
#pragma unroll
        for (int it = 0; it < AG / 256; it++) {
            int c = it * 256 + t;
            gl2lds16(Abase + (size_t)(c >> 2) * K + k0 + (c & 3) * 8, &As[sel][(c - l) * 8]);
        }
#pragma unroll
        for (int it = 0; it < BG / 256; it++) {
            int c = it * 256 + t;
            gl2lds16(Bbase + (size_t)(c >> 2) * K + k0 + (c & 3) * 8, &Bs[sel][(c - l) * 8]);
        }
    };

    stage(0, 0);
    __syncthreads();
    int cur = 0;
    for (int k0 = 0; k0 < K; k0 += 32) {
        if (k0 + 32 < K) stage(cur ^ 1, k0 + 32);
        bf16x8 af[MI], bfr[NI];
#pragma unroll
        for (int i = 0; i < MI; i++)
            af[i] = *(const bf16x8*)&As[cur][(wm + i * 16 + lane16) * 32 + quad * 8];
#pragma unroll
        for (int j = 0; j < NI; j++)
            bfr[j] = *(const bf16x8*)&Bs[cur][(wn + j * 16 + lane16) * 32 + quad * 8];
#pragma unroll
        for (int i = 0; i < MI; i++)
#pragma unroll
            for (int j = 0; j < NI; j++)
                acc[i][j] = __builtin_amdgcn_mfma_f32_16x16x32_bf16(af[i], bfr[j], acc[i][j], 0, 0, 0);
        __syncthreads();
        cur ^= 1;
    }
#pragma unroll
    for (int i = 0; i < MI; i++)
#pragma unroll
        for (int j = 0; j < NI; j++) {
            float* cp = C + (size_t)(m0 + wm + i * 16 + quad * 4) * Ndim + n0 + wn + j * 16 + lane16;
#pragma unroll
            for (int r = 0; r < 4; r++) cp[(size_t)r * Ndim] = acc[i][j][r];
        }
}

// ------- fused attn (R9 structure; solver cut to 5 sweeps: fused-max + 2AS + 2NW + ssum) ----
// Rationale: absmax was bit-identical (0.01757812) across Newton-12 / AS3+NW4 / AS3+NW3 —
// tau converges far below the bf16 noise floor, so the solver was over-iterating. On the
// correct support f(tau) is exactly quadratic and the AS step solves it exactly; NW only
// fixes residual support error. Each sweep costs a full spilled-xr reload, so -3 sweeps.
template <int SEGS>
__device__ __forceinline__ void attn_body(const bf16* __restrict__ qs, const bf16* __restrict__ kb,
                                          const bf16* __restrict__ vT, float* __restrict__ attn,
                                          bf16* __restrict__ o, int r0, int h,
                                          float (&buf)[16][BROW]) {
    constexpr int NREG2 = SEGS * 4;  // f32x2 regs per lane (= SEGS*8 scores)
    int jlen = r0 + 16;
    int l = threadIdx.x & 63;
    int w = threadIdx.x >> 6;  // 0..15
    int lane16 = l & 15, quad = l >> 4;

    const bf16* qrow = qs + ((size_t)h * S + (r0 + lane16)) * HD + quad * 8;
    bf16x8 afrag[4];
#pragma unroll
    for (int kc = 0; kc < 4; kc++) afrag[kc] = *(const bf16x8*)(qrow + kc * 32);

    const bf16* kbase = kb + (size_t)(h >> 2) * S * HD;
    const bf16* vbase = vT + (size_t)(h >> 2) * HD * S;
    f32x2 xr[NREG2];
    float mx = -1e30f;  // row max, fused into Phase A readback (values are in regs there)

    // ---- Phase A: scores into registers; single f32 buffer, 2 barriers/segment ----
#pragma unroll
    for (int sgi = 0; sgi < SEGS; sgi++) {
        int j0 = sgi * 512;
#pragma unroll
        for (int tt = 0; tt < 2; tt++) {
            int t = w + tt * 16;
            int jt = j0 + t * 16;
            if (jt < jlen) {
                f32x4 acc = {0.f, 0.f, 0.f, 0.f};
                const bf16* kp = kbase + (size_t)(jt + lane16) * HD + quad * 8;
#pragma unroll
                for (int kc = 0; kc < 4; kc++) {
                    bf16x8 b = *(const bf16x8*)(kp + kc * 32);
                    acc = __builtin_amdgcn_mfma_f32_16x16x32_bf16(afrag[kc], b, acc, 0, 0, 0);
                }
                if (jt + 15 > r0) {  // diagonal tile: apply causal mask
                    int jj = jt + lane16;
#pragma unroll
                    for (int r = 0; r < 4; r++) {
                        int rowi = quad * 4 + r;
                        float v = acc[r];
                        if (jj > r0 + rowi) v = -1e30f;
                        buf[rowi][t * 16 + lane16] = v;
                    }
                } else {
#pragma unroll
                    for (int r = 0; r < 4; r++) buf[quad * 4 + r][t * 16 + lane16] = acc[r];
                }
            }
        }
        __syncthreads();
#pragma unroll
        for (int part = 0; part < 2; part++) {
            float4 fq = *(const float4*)&buf[w][part * 256 + l * 4];
            f32x2 lo, hi;
            if (sgi == SEGS - 1) {
                int jb = j0 + part * 256 + l * 4;
                lo = (f32x2){(jb + 0 < jlen) ? fq.x : -1e30f, (jb + 1 < jlen) ? fq.y : -1e30f};
                hi = (f32x2){(jb + 2 < jlen) ? fq.z : -1e30f, (jb + 3 < jlen) ? fq.w : -1e30f};
            } else {
                lo = (f32x2){fq.x, fq.y};
                hi = (f32x2){fq.z, fq.w};
            }
            mx = fmaxf(mx, fmaxf(fmaxf(lo[0], lo[1]), fmaxf(hi[0], hi[1])));
            xr[sgi * 4 + part * 2 + 0] = lo;
            xr[sgi * 4 + part * 2 + 1] = hi;
        }
        __syncthreads();
    }

    float* arow = attn + ((size_t)h * S + (r0 + w)) * S;

    // ---- Phase E (early; tau-independent): zero-fill strictly-upper region ----
    {
        f32x4 z4 = {0.f, 0.f, 0.f, 0.f};
        for (int j = SEGS * 512 + l * 4; j < S; j += 256) nt_store4(z4, &arow[j]);
    }

    // ---- Phase B: entmax-1.5 tau: 2 active-set steps + 2 Newton polish ----
    const f32x2 z2 = {0.f, 0.f};
    float m = wave_fmax(mx);
    float taulo = m - 1.0f;
    float tauhi = m - 0.02209709f;  // m - (1/2048)^0.5
    float tau = taulo;

#pragma unroll 1
    for (int it = 0; it < AS_ITERS; it++) {
        f32x2 tvi = {tau, tau};
        f32x2 b1a = z2, b1b = z2, b2a = z2, b2b = z2, cna = z2, cnb = z2;
#pragma unroll
        for (int c = 0; c < NREG2; c += 2) {
            f32x2 t0 = __builtin_elementwise_max(xr[c] - tvi, z2);
            b2a += t0 * t0; b1a += t0;
            cna += (f32x2){t0[0] > 0.f ? 1.f : 0.f, t0[1] > 0.f ? 1.f : 0.f};
            f32x2 t1 = __builtin_elementwise_max(xr[c + 1] - tvi, z2);
            b2b += t1 * t1; b1b += t1;
            cnb += (f32x2){t1[0] > 0.f ? 1.f : 0.f, t1[1] > 0.f ? 1.f : 0.f};
        }
        f32x2 s1 = b1a + b1b, s2 = b2a + b2b, sc = cna + cnb;
        float B1 = wave_sum(s1[0] + s1[1]);
        float B2 = wave_sum(s2[0] + s2[1]);
        float n = wave_sum(sc[0] + sc[1]);
        float disc = fmaxf(B1 * B1 - n * (B2 - 1.0f), 0.f);
        tau += (B1 - __builtin_sqrtf(disc)) / fmaxf(n, 1.0f);
        tau = fminf(fmaxf(tau, taulo), tauhi);
    }
#pragma unroll 1
    for (int it = 0; it < NW_ITERS; it++) {
        f32x2 tvi = {tau, tau};
        f32x2 fa = z2, fb = z2, ga = z2, gb = z2;
#pragma unroll
        for (int c = 0; c < NREG2; c += 2) {
            f32x2 t0 = __builtin_elementwise_max(xr[c] - tvi, z2);
            fa += t0 * t0; ga += t0;
            f32x2 t1 = __builtin_elementwise_max(xr[c + 1] - tvi, z2);
            fb += t1 * t1; gb += t1;
        }
        f32x2 fv = fa + fb, gv = ga + gb;
        float f = wave_sum(fv[0] + fv[1]);
        float g = wave_sum(gv[0] + gv[1]);
        tau += (f - 1.0f) / (2.0f * g + 1e-20f);
        tau = fminf(fmaxf(tau, taulo), tauhi);
    }

    f32x2 tv = {tau, tau};
    float inv;
    {
        f32x2 sa = z2, sbv = z2;
#pragma unroll
        for (int c = 0; c < NREG2; c += 2) {
            f32x2 t0 = __builtin_elementwise_max(xr[c] - tv, z2);
            sa += t0 * t0;
            f32x2 t1 = __builtin_elementwise_max(xr[c + 1] - tv, z2);
            sbv += t1 * t1;
        }
        f32x2 sv = sa + sbv;
        float ssum = wave_sum(sv[0] + sv[1]);
        inv = 1.0f / ssum;
    }

    // ---- Phase C: P f32 -> attn global (fused; xr dies here) + P bf16 -> LDS
    //      (ping-pong halves), P.V MFMA; 1 barrier/segment ----
    int jt_o = (w & 7) * 16;
    int kh = (w >> 3) * 256;
    f32x4 acc_o = {0.f, 0.f, 0.f, 0.f};
    f32x2 inv2 = {inv, inv};

#pragma unroll
    for (int sgi = 0; sgi < SEGS; sgi++) {
        int j0 = sgi * 512;
        bf16 (*pb)[BROW] = (bf16(*)[BROW])(&buf[0][0]) + (sgi & 1) * 16;
#pragma unroll
        for (int part = 0; part < 2; part++) {
            f32x2 ta = __builtin_elementwise_max(xr[sgi * 4 + part * 2 + 0] - tv, z2);
            f32x2 tb = __builtin_elementwise_max(xr[sgi * 4 + part * 2 + 1] - tv, z2);
            f32x2 pa = (ta * ta) * inv2;
            f32x2 pb2 = (tb * tb) * inv2;
            f32x4 pv = {pa[0], pa[1], pb2[0], pb2[1]};
            nt_store4(pv, &arow[j0 + part * 256 + l * 4]);
            bf16x4 pbv;
            pbv[0] = (bf16)pv[0]; pbv[1] = (bf16)pv[1];
            pbv[2] = (bf16)pv[2]; pbv[3] = (bf16)pv[3];
            *(bf16x4*)&pb[w][part * 256 + l * 4] = pbv;
        }
        __syncthreads();
#pragma unroll
        for (int ks = 0; ks < 8; ks++) {
            int kk = kh + ks * 32;
            bf16x8 a = *(const bf16x8*)&pb[lane16][kk + quad * 8];
            bf16x8 b = *(const bf16x8*)(vbase + (size_t)(jt_o + lane16) * S + j0 + kk + quad * 8);
            acc_o = __builtin_amdgcn_mfma_f32_16x16x32_bf16(a, b, acc_o, 0, 0, 0);
        }
    }

    // ---- Phase D: combine K-halves, write O ----
    __syncthreads();
    if (w >= 8) {
#pragma unroll
        for (int r = 0; r < 4; r++) buf[w - 8][l * 4 + r] = acc_o[r];
    }
    __syncthreads();
    if (w < 8) {
        bf16* op = o + (size_t)(r0 + quad * 4) * DM + h * HD + jt_o + lane16;
#pragma unroll
        for (int r = 0; r < 4; r++) {
            float v = acc_o[r] + buf[w][l * 4 + r];
            op[(size_t)r * DM] = (bf16)v;
        }
    }
}

// 512 persistent blocks (2/CU), classes {4,3,2,1} = 10 segments/block, uniform.
__global__ __launch_bounds__(1024, 8) void attn_av_all(const bf16* __restrict__ qs,
                                                       const bf16* __restrict__ kb,
                                                       const bf16* __restrict__ vT,
                                                       float* __restrict__ attn,
                                                       bf16* __restrict__ o) {
    __shared__ float buf[16][BROW];
    int b = blockIdx.x;
    int h = b & 15;
    int qh = b >> 4;
    attn_body<4>(qs, kb, vT, attn, o, (96 + qh) * 16, h, buf);
    __syncthreads();
    attn_body<3>(qs, kb, vT, attn, o, (64 + qh) * 16, h, buf);
    __syncthreads();
    attn_body<2>(qs, kb, vT, attn, o, (32 + qh) * 16, h, buf);
    __syncthreads();
    attn_body<1>(qs, kb, vT, attn, o, qh * 16, h, buf);
}

extern "C" void kernel_launch(void* const* d_in, const int* in_sizes, int n_in,
                              void* d_out, int out_size, void* d_ws, size_t ws_size,
                              hipStream_t stream) {
    const float* hidden = (const float*)d_in[0];
    const float* cosb   = (const float*)d_in[1];
    const float* sinb   = (const float*)d_in[2];
    const float* wq     = (const float*)d_in[3];
    const float* wk     = (const float*)d_in[4];
    const float* wv     = (const float*)d_in[5];
    const float* wo     = (const float*)d_in[6];
    char* ws = (char*)d_ws;
    bf16*  bf_hidden = (bf16*)(ws);                    // 8 MB; reused as O bf16 later
    bf16*  bf_wqkv   = (bf16*)(ws + 8388608);          // 12 MB
    bf16*  bf_wo     = (bf16*)(ws + 20971520);         // 8 MB
    bf16*  qsb       = (bf16*)(ws + 29360128);         // 8 MB  [H][S][HD]
    bf16*  kbb       = (bf16*)(ws + 37748736);         // 2 MB  [4][S][HD]
    bf16*  vTb       = (bf16*)(ws + 39845888);         // 2 MB  [4][HD][S]
    float* out  = (float*)d_out;
    float* attn = out + 4194304;

    cvt_all<<<dim3(14336), 256, 0, stream>>>(hidden, wq, wk, wv, wo, bf_hidden, bf_wqkv, bf_wo);

    // QKV projection with fused RoPE + V-transpose epilogue (768 blocks = 3/CU balanced)
    gemm_qkv_rope<<<dim3(32, 24), 256, 0, stream>>>(bf_hidden, bf_wqkv, cosb, sinb,
                                                    qsb, kbb, vTb);

    // fused scores + entmax + P.V + attn write  (512 persistent blocks, 2/CU)
    attn_av_all<<<dim3(512), 1024, 0, stream>>>(qsb, kbb, vTb, attn, bf_hidden);

    // out = O @ wo^T  (512 blocks = 2/CU balanced)
    gemm_bt<64, 128><<<dim3(32, 16), 256, 0, stream>>>(bf_hidden, bf_wo, out, DM, DM);
}